// Round 3
// baseline (8213.658 us; speedup 1.0000x reference)
//
#include <hip/hip_runtime.h>
#include <hip/hip_bf16.h>

typedef unsigned short u16;
typedef unsigned int   u32;
typedef unsigned char  u8;

static __device__ __forceinline__ float bf2f(u16 u){ return __uint_as_float(((u32)u)<<16); }
static __device__ __forceinline__ u16 f2bf(float f){
  u32 u = __float_as_uint(f);
  u32 r = (u + 0x7fff + ((u>>16)&1)) >> 16;   // RNE; inputs are finite
  return (u16)r;
}
static __device__ __forceinline__ float h2f(u16 v){ union{u16 u; _Float16 h;} c; c.u=v; return (float)c.h; }

// ---------------------------------------------------------------------------
// K0: convert Wc/Wd (f32) -> bf16 workspace copies.
// ---------------------------------------------------------------------------
__global__ void k_wcvt(const float* __restrict__ Wc, const float* __restrict__ Wd,
                       u16* __restrict__ Wcb, u16* __restrict__ Wdb){
  size_t i = ((size_t)blockIdx.x*256 + threadIdx.x)*4;
  const float* src = blockIdx.y ? Wd : Wc;
  u16* dst = blockIdx.y ? Wdb : Wcb;
  float4 v = *(const float4*)(src + i);
  u32 lo = (u32)f2bf(v.x) | ((u32)f2bf(v.y)<<16);
  u32 hi = (u32)f2bf(v.z) | ((u32)f2bf(v.w)<<16);
  *(uint2*)(dst + i) = make_uint2(lo, hi);
}

// ---------------------------------------------------------------------------
// K1: row n of A = E E^T (f32 inputs). Writes sign-mask (1 pos, 2 neg, 0 zero)
// and P = softmax(relu(A),axis=1) as bf16. One block per row.
// ---------------------------------------------------------------------------
__global__ void k_P(const float* __restrict__ E, u16* __restrict__ P, u8* __restrict__ msk){
  __shared__ float Ew[16];
  __shared__ float arow[2048];
  __shared__ float red[4];
  const int t = threadIdx.x, n = blockIdx.x;
  if (t < 16) Ew[t] = E[n*16 + t];
  __syncthreads();
  float lmax = 0.f;
  for (int i=0;i<8;i++){
    int m = t + 256*i;
    const float* ep = E + m*16;
    float dot = 0.f;
    #pragma unroll
    for (int d=0; d<16; ++d) dot += Ew[d]*ep[d];
    msk[n*2048 + m] = dot > 0.f ? (u8)1 : (dot < 0.f ? (u8)2 : (u8)0);
    float ar = fmaxf(dot, 0.f);
    arow[m] = ar;
    lmax = fmaxf(lmax, ar);
  }
  for (int o=1;o<64;o<<=1) lmax = fmaxf(lmax, __shfl_xor(lmax, o));
  if ((t&63)==0) red[t>>6] = lmax;
  __syncthreads();
  float gmax = fmaxf(fmaxf(red[0],red[1]), fmaxf(red[2],red[3]));
  __syncthreads();
  float lsum = 0.f;
  for (int i=0;i<8;i++){
    int m = t + 256*i;
    float e = expf(arow[m] - gmax);
    arow[m] = e;
    lsum += e;
  }
  for (int o=1;o<64;o<<=1) lsum += __shfl_xor(lsum, o);
  if ((t&63)==0) red[t>>6] = lsum;
  __syncthreads();
  float inv = 1.f/(red[0]+red[1]+red[2]+red[3]);
  for (int i=0;i<8;i++){
    int m = t + 256*i;
    P[n*2048 + m] = f2bf(arow[m]*inv);
  }
}

// ---------------------------------------------------------------------------
// K2x: c1x[b,n,c] = sum_m P[n,m] * x[b,m,c]   (c = 0..1), x f32
// ---------------------------------------------------------------------------
__global__ void k_c1x(const u16* __restrict__ P, const float* __restrict__ x, float* __restrict__ c1x){
  const int t = threadIdx.x;
  const int r = t>>1, c = t&1;
  const int n = blockIdx.x*64 + r, b = blockIdx.y;
  const u16* pr = P + (size_t)n*2048;
  const float* xb = x + (size_t)b*2048*2 + c;
  float acc = 0.f;
  for (int m=0;m<2048;m+=4){
    acc += bf2f(pr[m+0])*xb[(m+0)*2];
    acc += bf2f(pr[m+1])*xb[(m+1)*2];
    acc += bf2f(pr[m+2])*xb[(m+2)*2];
    acc += bf2f(pr[m+3])*xb[(m+3)*2];
  }
  c1x[((size_t)b*2048 + n)*2 + c] = acc;
}

// ---------------------------------------------------------------------------
// K2: Y[b,n,d] = sum_m P[n,m] * Z[b,m,d], Z f32 [B,N,64]. 64x64 tile.
// ---------------------------------------------------------------------------
__global__ void k_conv(const u16* __restrict__ P, const float* __restrict__ Z, float* __restrict__ Y){
  __shared__ float Pt[16][68];
  __shared__ float Zt[16][68];
  const int t = threadIdx.x;
  const int tr = t>>4, tc = t&15;
  const int n0 = blockIdx.x*64, b = blockIdx.y;
  float acc[4][4] = {};
  for (int mt=0; mt<128; ++mt){
    int m0 = mt*16;
    {
      int r = t>>2, c4 = (t&3)*4;
      const u16* pp = P + (size_t)(n0+r)*2048 + m0 + c4;
      u32 p0 = *(const u32*)pp, p1v = *(const u32*)(pp+2);
      Pt[c4+0][r]=bf2f((u16)p0);  Pt[c4+1][r]=bf2f((u16)(p0>>16));
      Pt[c4+2][r]=bf2f((u16)p1v); Pt[c4+3][r]=bf2f((u16)(p1v>>16));
      int mm = t>>4, d0 = (t&15)*4;
      float4 zv = *(const float4*)&Z[((size_t)b*2048 + m0+mm)*64 + d0];
      Zt[mm][d0+0]=zv.x; Zt[mm][d0+1]=zv.y; Zt[mm][d0+2]=zv.z; Zt[mm][d0+3]=zv.w;
    }
    __syncthreads();
    #pragma unroll
    for (int mm=0; mm<16; ++mm){
      float4 a  = *(const float4*)&Pt[mm][tr*4];
      float4 bz = *(const float4*)&Zt[mm][tc*4];
      acc[0][0]+=a.x*bz.x; acc[0][1]+=a.x*bz.y; acc[0][2]+=a.x*bz.z; acc[0][3]+=a.x*bz.w;
      acc[1][0]+=a.y*bz.x; acc[1][1]+=a.y*bz.y; acc[1][2]+=a.y*bz.z; acc[1][3]+=a.y*bz.w;
      acc[2][0]+=a.z*bz.x; acc[2][1]+=a.z*bz.y; acc[2][2]+=a.z*bz.z; acc[2][3]+=a.z*bz.w;
      acc[3][0]+=a.w*bz.x; acc[3][1]+=a.w*bz.y; acc[3][2]+=a.w*bz.z; acc[3][3]+=a.w*bz.w;
    }
    __syncthreads();
  }
  #pragma unroll
  for (int i=0;i<4;i++){
    float4 v = make_float4(acc[i][0],acc[i][1],acc[i][2],acc[i][3]);
    *(float4*)&Y[((size_t)b*2048 + n0 + tr*4 + i)*64 + tc*4] = v;
  }
}

// ---------------------------------------------------------------------------
// K3: gate SAGC -> zs = z*state, rws = r. One block per node n. All-f32 inputs.
// ---------------------------------------------------------------------------
__global__ void k_gate(const float* __restrict__ E, const float* __restrict__ gw, const float* __restrict__ gb,
                       const float* __restrict__ x, const float* __restrict__ state,
                       const float* __restrict__ c1x, const float* __restrict__ c1s,
                       float* __restrict__ zs, float* __restrict__ rws){
  __shared__ float Ew[16];
  __shared__ float bnv[128];
  __shared__ float Wn[2][66][64];
  __shared__ float xg4[4][2][66];
  const int t = threadIdx.x, n = blockIdx.x;
  if (t < 16) Ew[t] = E[n*16 + t];
  __syncthreads();
  if (t < 128){
    float a = 0.f;
    #pragma unroll
    for (int e=0;e<16;e++) a += Ew[e]*gb[e*128 + t];
    bnv[t] = a;
  }
  for (int half=0; half<2; ++half){
    for (int idx=t; idx<8448; idx+=256){
      int o = idx & 63, rest = idx>>6, i = rest % 66, k = rest / 66;
      float a = 0.f;
      #pragma unroll
      for (int e=0;e<16;e++) a += Ew[e]*gw[((e*2+k)*66 + i)*128 + half*64 + o];
      Wn[k][i][o] = a;
    }
    __syncthreads();
    for (int bb=0; bb<4; ++bb){
      for (int idx=t; idx<528; idx+=256){
        int bi = idx/132, rem = idx%132, k = rem/66, i = rem%66;
        int b = bb*4 + bi;
        float v;
        if (k==0) v = (i<2) ? x[((size_t)b*2048+n)*2 + i] : state[((size_t)b*2048+n)*64 + (i-2)];
        else      v = (i<2) ? c1x[((size_t)b*2048+n)*2 + i] : c1s[((size_t)b*2048+n)*64 + (i-2)];
        xg4[bi][k][i] = v;
      }
      __syncthreads();
      {
        int bi = t>>6, o = t&63, b = bb*4 + bi;
        float a = 0.f;
        #pragma unroll
        for (int k=0;k<2;k++)
          for (int i=0;i<66;i++) a += xg4[bi][k][i]*Wn[k][i][o];
        a += bnv[half*64 + o];
        float s = 1.f/(1.f + expf(-a));
        if (half==0) zs[((size_t)b*2048+n)*64 + o] = s*state[((size_t)b*2048+n)*64 + o];
        else         rws[((size_t)b*2048+n)*64 + o] = s;
      }
      __syncthreads();
    }
  }
}

// ---------------------------------------------------------------------------
// K3b: update SAGC -> hc -> h = r*state + (1-r)*hc.
// ---------------------------------------------------------------------------
__global__ void k_upd(const float* __restrict__ E, const float* __restrict__ uw, const float* __restrict__ ub,
                      const float* __restrict__ x, const float* __restrict__ state,
                      const float* __restrict__ zs, const float* __restrict__ c1x, const float* __restrict__ c2s,
                      const float* __restrict__ rws, float* __restrict__ h){
  __shared__ float Ew[16];
  __shared__ float bnu[64];
  __shared__ float Wn[2][66][64];
  __shared__ float xg4[4][2][66];
  const int t = threadIdx.x, n = blockIdx.x;
  if (t < 16) Ew[t] = E[n*16 + t];
  __syncthreads();
  if (t < 64){
    float a = 0.f;
    #pragma unroll
    for (int e=0;e<16;e++) a += Ew[e]*ub[e*64 + t];
    bnu[t] = a;
  }
  for (int idx=t; idx<8448; idx+=256){
    int o = idx & 63, rest = idx>>6, i = rest % 66, k = rest / 66;
    float a = 0.f;
    #pragma unroll
    for (int e=0;e<16;e++) a += Ew[e]*uw[((e*2+k)*66 + i)*64 + o];
    Wn[k][i][o] = a;
  }
  __syncthreads();
  for (int bb=0; bb<4; ++bb){
    for (int idx=t; idx<528; idx+=256){
      int bi = idx/132, rem = idx%132, k = rem/66, i = rem%66;
      int b = bb*4 + bi;
      float v;
      if (k==0) v = (i<2) ? x[((size_t)b*2048+n)*2 + i] : zs[((size_t)b*2048+n)*64 + (i-2)];
      else      v = (i<2) ? c1x[((size_t)b*2048+n)*2 + i] : c2s[((size_t)b*2048+n)*64 + (i-2)];
      xg4[bi][k][i] = v;
    }
    __syncthreads();
    {
      int bi = t>>6, o = t&63, b = bb*4 + bi;
      float a = 0.f;
      #pragma unroll
      for (int k=0;k<2;k++)
        for (int i=0;i<66;i++) a += xg4[bi][k][i]*Wn[k][i][o];
      float hc = tanhf(a + bnu[o]);
      float rv = rws[((size_t)b*2048+n)*64 + o];
      h[((size_t)b*2048+n)*64 + o] = rv*state[((size_t)b*2048+n)*64 + o] + (1.f - rv)*hc;
    }
    __syncthreads();
  }
}

// ---------------------------------------------------------------------------
// K5: fused degrees, 8-row tiles, all-static LDS (~43 KB). W is bf16 (ws copy).
// grid (256, B, 2); block 256.
// ---------------------------------------------------------------------------
#define SROW 2056   // halves per S row (2048 + 8 pad)

__global__ void __launch_bounds__(256) k_deg(const u8* __restrict__ msk, const float* __restrict__ h,
                      const u16* __restrict__ Wc, const u16* __restrict__ Wd,
                      float* __restrict__ outc, float* __restrict__ outd){
  __shared__ _Float16 S[8*SROW];       // 32,896 B
  __shared__ float qv[8*64];           //  2,048 B
  __shared__ float red_s[8][4];        //    128 B
  __shared__ float red4[4*8*64];       //  8,192 B
  const int t = threadIdx.x;
  const int n0 = blockIdx.x*8, b = blockIdx.y, mask = blockIdx.z;
  const u16* W = mask ? Wd : Wc;
  const u8 want = mask ? (u8)2 : (u8)1;
  const float* hb = h + (size_t)b*2048*64;

  if (t < 128)
    ((float4*)qv)[t] = *(const float4*)&hb[(size_t)(n0 + (t>>4))*64 + (t&15)*4];
  __syncthreads();

  // ---- phase 1: S[r][m] = mask ? h_{n0+r} . h_m : 0 ----
  {
    float p1[8][8];
    #pragma unroll
    for (int r=0;r<8;r++)
      #pragma unroll
      for (int i=0;i<8;i++) p1[r][i] = 0.f;
    for (int d4=0; d4<16; ++d4){
      float4 q4[8];
      #pragma unroll
      for (int r=0;r<8;r++) q4[r] = *(const float4*)&qv[r*64 + d4*4];
      #pragma unroll
      for (int mi=0; mi<8; ++mi){
        int m = t + 256*mi;
        float4 hv = *(const float4*)&hb[(size_t)m*64 + d4*4];
        #pragma unroll
        for (int r=0;r<8;r++)
          p1[r][mi] += q4[r].x*hv.x + q4[r].y*hv.y + q4[r].z*hv.z + q4[r].w*hv.w;
      }
    }
    #pragma unroll
    for (int mi=0; mi<8; ++mi){
      int m = t + 256*mi;
      #pragma unroll
      for (int r=0;r<8;r++){
        bool keep = (msk[(size_t)(n0+r)*2048 + m] == want);
        S[r*SROW + m] = (_Float16)(keep ? p1[r][mi] : 0.f);
      }
    }
  }
  __syncthreads();

  // ---- phase 2: L[r][k] = sum_m S[r][m] W[m][k]; thread owns k in {2t,2t+1}+512j ----
  float acc[8][8];
  #pragma unroll
  for (int r=0;r<8;r++)
    #pragma unroll
    for (int j=0;j<8;j++) acc[r][j] = 0.f;
  for (int mblk=0; mblk<512; ++mblk){
    int m = mblk*4;
    uint2 srow[8];
    #pragma unroll
    for (int r=0;r<8;r++) srow[r] = *(const uint2*)(S + r*SROW + m);
    #pragma unroll
    for (int mm=0; mm<4; ++mm){
      const u16* wr = W + (size_t)(m+mm)*2048;
      u32 wq[4];
      #pragma unroll
      for (int j=0;j<4;j++) wq[j] = *(const u32*)&wr[2*t + 512*j];
      float s[8];
      #pragma unroll
      for (int r=0;r<8;r++){
        u32 wb = (mm & 2) ? srow[r].y : srow[r].x;
        s[r] = h2f((mm & 1) ? (u16)(wb>>16) : (u16)wb);
      }
      float wlo[4], whi[4];
      #pragma unroll
      for (int j=0;j<4;j++){
        wlo[j] = __uint_as_float(wq[j]<<16);
        whi[j] = __uint_as_float(wq[j] & 0xffff0000u);
      }
      #pragma unroll
      for (int r=0;r<8;r++)
        #pragma unroll
        for (int j=0;j<4;j++){
          acc[r][2*j]   += s[r]*wlo[j];
          acc[r][2*j+1] += s[r]*whi[j];
        }
    }
  }

  // ---- phase 3: row softmax over k ----
  const int lane = t & 63, wv = t >> 6;
  float gmax[8], inv[8];
  #pragma unroll
  for (int r=0;r<8;r++){
    float mx = acc[r][0];
    #pragma unroll
    for (int j=1;j<8;j++) mx = fmaxf(mx, acc[r][j]);
    for (int o=1;o<64;o<<=1) mx = fmaxf(mx, __shfl_xor(mx, o));
    if (lane==0) red_s[r][wv] = mx;
  }
  __syncthreads();
  #pragma unroll
  for (int r=0;r<8;r++) gmax[r] = fmaxf(fmaxf(red_s[r][0],red_s[r][1]), fmaxf(red_s[r][2],red_s[r][3]));
  __syncthreads();
  #pragma unroll
  for (int r=0;r<8;r++){
    float ls = 0.f;
    #pragma unroll
    for (int j=0;j<8;j++){ acc[r][j] = expf(acc[r][j] - gmax[r]); ls += acc[r][j]; }
    for (int o=1;o<64;o<<=1) ls += __shfl_xor(ls, o);
    if (lane==0) red_s[r][wv] = ls;
  }
  __syncthreads();
  #pragma unroll
  for (int r=0;r<8;r++) inv[r] = 1.f/(red_s[r][0]+red_s[r][1]+red_s[r][2]+red_s[r][3]);
  #pragma unroll
  for (int r=0;r<8;r++)
    #pragma unroll
    for (int jj=0;jj<4;jj++){
      int k = 2*t + 512*jj;
      S[r*SROW + k]     = (_Float16)(acc[r][2*jj]  *inv[r]);
      S[r*SROW + k + 1] = (_Float16)(acc[r][2*jj+1]*inv[r]);
    }
  __syncthreads();

  // ---- phase 4: out[r][d] = sum_k deg[r][k] h[b][k][d] ----
  {
    const int ks = t>>6, rr = (t>>4)&3, dg = t&15;
    float o4[2][4];
    #pragma unroll
    for (int i=0;i<2;i++)
      #pragma unroll
      for (int j=0;j<4;j++) o4[i][j] = 0.f;
    for (int k = ks*512; k < ks*512 + 512; k += 4){
      float dgv[2][4];
      #pragma unroll
      for (int ri=0; ri<2; ++ri){
        uint2 dv = *(const uint2*)(S + (rr*2+ri)*SROW + k);
        dgv[ri][0] = h2f((u16)dv.x); dgv[ri][1] = h2f((u16)(dv.x>>16));
        dgv[ri][2] = h2f((u16)dv.y); dgv[ri][3] = h2f((u16)(dv.y>>16));
      }
      #pragma unroll
      for (int kk=0; kk<4; ++kk){
        float4 hv = *(const float4*)&hb[(size_t)(k+kk)*64 + dg*4];
        #pragma unroll
        for (int ri=0; ri<2; ++ri){
          o4[ri][0] += dgv[ri][kk]*hv.x;
          o4[ri][1] += dgv[ri][kk]*hv.y;
          o4[ri][2] += dgv[ri][kk]*hv.z;
          o4[ri][3] += dgv[ri][kk]*hv.w;
        }
      }
    }
    #pragma unroll
    for (int ri=0;ri<2;ri++)
      #pragma unroll
      for (int dd=0;dd<4;dd++)
        red4[(ks*8 + rr*2+ri)*64 + dg*4+dd] = o4[ri][dd];
    __syncthreads();
    if (t < 128){
      int r = t>>4, d0 = (t&15)*4;
      float4 s0 = *(float4*)&red4[(0*8+r)*64 + d0];
      float4 s1 = *(float4*)&red4[(1*8+r)*64 + d0];
      float4 s2 = *(float4*)&red4[(2*8+r)*64 + d0];
      float4 s3 = *(float4*)&red4[(3*8+r)*64 + d0];
      float4 o;
      o.x = s0.x+s1.x+s2.x+s3.x;
      o.y = s0.y+s1.y+s2.y+s3.y;
      o.z = s0.z+s1.z+s2.z+s3.z;
      o.w = s0.w+s1.w+s2.w+s3.w;
      float* op = (mask ? outd : outc) + ((size_t)b*2048 + n0 + r)*64 + d0;
      *(float4*)op = o;
    }
  }
}

// ---------------------------------------------------------------------------
// K6: numerator = 0.8h - 0.1 outc + 0.1 outd  -> f32 output
// ---------------------------------------------------------------------------
__global__ void k_final(const float* __restrict__ h, const float* __restrict__ outc,
                        const float* __restrict__ outd, float* __restrict__ out){
  size_t i = (size_t)blockIdx.x*256 + threadIdx.x;
  out[i] = 0.8f*h[i] - 0.1f*outc[i] + 0.1f*outd[i];
}

// ---------------------------------------------------------------------------
extern "C" void kernel_launch(void* const* d_in, const int* in_sizes, int n_in,
                              void* d_out, int out_size, void* d_ws, size_t ws_size,
                              hipStream_t stream) {
  const float* x     = (const float*)d_in[0];
  const float* state = (const float*)d_in[1];
  const float* E     = (const float*)d_in[2];
  const float* Wc    = (const float*)d_in[3];
  const float* Wd    = (const float*)d_in[4];
  const float* gw    = (const float*)d_in[5];
  const float* gb    = (const float*)d_in[6];
  const float* uw    = (const float*)d_in[7];
  const float* ub    = (const float*)d_in[8];

  // workspace layout (float units). Total 17,891,328 floats = 71.6 MB.
  float* ws  = (float*)d_ws;
  u16*   P    = (u16*)ws;                       // 2048*2048 bf16  -> 2,097,152 f
  u8*    msk  = (u8*)(ws + 2097152);            // 2048*2048 u8    -> 1,048,576 f
  u16*   Wcb  = (u16*)(ws + 3145728);           // 2048*2048 bf16  -> 2,097,152 f
  u16*   Wdb  = (u16*)(ws + 5242880);           // 2048*2048 bf16  -> 2,097,152 f
  float* c1x  = ws + 7340032;                   //    65,536 f
  float* c1s  = ws + 7405568;                   // 2,097,152 f
  float* zs   = ws + 9502720;                   // 2,097,152 f
  float* rws  = ws + 11599872;                  // 2,097,152 f
  float* c2s  = ws + 13697024;                  // 2,097,152 f
  float* h    = ws + 15794176;                  // 2,097,152 f
  float* oc   = c1s;                            // dead after k_gate
  float* od   = c2s;                            // dead after k_upd

  k_wcvt<<<dim3(4096,2), 256, 0, stream>>>(Wc, Wd, Wcb, Wdb);
  k_P<<<2048, 256, 0, stream>>>(E, P, msk);
  k_c1x<<<dim3(32,16), 128, 0, stream>>>(P, x, c1x);
  k_conv<<<dim3(32,16), 256, 0, stream>>>(P, state, c1s);
  k_gate<<<2048, 256, 0, stream>>>(E, gw, gb, x, state, c1x, c1s, zs, rws);
  k_conv<<<dim3(32,16), 256, 0, stream>>>(P, zs, c2s);
  k_upd<<<2048, 256, 0, stream>>>(E, uw, ub, x, state, zs, c1x, c2s, rws, h);
  k_deg<<<dim3(256,16,2), 256, 0, stream>>>(msk, h, Wcb, Wdb, oc, od);
  k_final<<<8192, 256, 0, stream>>>(h, oc, od, (float*)d_out);
}

// Round 4
// 3826.751 us; speedup vs baseline: 2.1464x; 2.1464x over previous
//
#include <hip/hip_runtime.h>
#include <hip/hip_bf16.h>

typedef unsigned short u16;
typedef unsigned int   u32;
typedef unsigned char  u8;

typedef __attribute__((ext_vector_type(8))) short bf16x8;
typedef __attribute__((ext_vector_type(4))) float f32x4;

static __device__ __forceinline__ float bf2f(u16 u){ return __uint_as_float(((u32)u)<<16); }
static __device__ __forceinline__ u16 f2bf(float f){
  u32 u = __float_as_uint(f);
  u32 r = (u + 0x7fff + ((u>>16)&1)) >> 16;   // RNE; inputs finite
  return (u16)r;
}

static __device__ __forceinline__ bf16x8 pack_bf8(const float* __restrict__ p){
  float4 a = *(const float4*)p, b = *(const float4*)(p+4);
  bf16x8 r;
  r[0]=(short)f2bf(a.x); r[1]=(short)f2bf(a.y); r[2]=(short)f2bf(a.z); r[3]=(short)f2bf(a.w);
  r[4]=(short)f2bf(b.x); r[5]=(short)f2bf(b.y); r[6]=(short)f2bf(b.z); r[7]=(short)f2bf(b.w);
  return r;
}

// ---------------------------------------------------------------------------
// K-1: tiled transpose W (f32 [m][c]) -> Wt (bf16 [c][m]).  grid (32,32,2).
// ---------------------------------------------------------------------------
__global__ void k_wt(const float* __restrict__ Wc, const float* __restrict__ Wd,
                     u16* __restrict__ Wct, u16* __restrict__ Wdt){
  __shared__ float tile[64][65];
  const float* src = blockIdx.z ? Wd : Wc;
  u16* dst = blockIdx.z ? Wdt : Wct;
  const int m0 = blockIdx.x*64, c0 = blockIdx.y*64;
  const int t = threadIdx.x, r = t & 63, cc = t >> 6;
  #pragma unroll
  for (int j=0;j<4;j++){
    float4 v = *(const float4*)&src[(size_t)(m0+r)*2048 + c0 + cc*16 + j*4];
    tile[r][cc*16+j*4+0]=v.x; tile[r][cc*16+j*4+1]=v.y;
    tile[r][cc*16+j*4+2]=v.z; tile[r][cc*16+j*4+3]=v.w;
  }
  __syncthreads();
  u16 ov[16];
  #pragma unroll
  for (int jj=0;jj<16;jj++) ov[jj] = f2bf(tile[cc*16+jj][r]);
  u32 w8[8];
  #pragma unroll
  for (int p=0;p<8;p++) w8[p] = (u32)ov[2*p] | ((u32)ov[2*p+1]<<16);
  u16* dp = dst + (size_t)(c0+r)*2048 + m0 + cc*16;
  *(uint4*)dp     = make_uint4(w8[0],w8[1],w8[2],w8[3]);
  *(uint4*)(dp+8) = make_uint4(w8[4],w8[5],w8[6],w8[7]);
}

// ---------------------------------------------------------------------------
// K-ht: h (f32 [b][k][d]) -> ht (bf16 [b][d][k]).  grid (32,16).
// ---------------------------------------------------------------------------
__global__ void k_ht(const float* __restrict__ h, u16* __restrict__ ht){
  __shared__ float tile[64][65];
  const int k0 = blockIdx.x*64, b = blockIdx.y;
  const int t = threadIdx.x, r = t & 63, cc = t >> 6;
  const float* src = h + ((size_t)b*2048 + k0)*64;
  #pragma unroll
  for (int j=0;j<4;j++){
    float4 v = *(const float4*)&src[(size_t)r*64 + cc*16 + j*4];
    tile[r][cc*16+j*4+0]=v.x; tile[r][cc*16+j*4+1]=v.y;
    tile[r][cc*16+j*4+2]=v.z; tile[r][cc*16+j*4+3]=v.w;
  }
  __syncthreads();
  u16 ov[16];
  #pragma unroll
  for (int jj=0;jj<16;jj++) ov[jj] = f2bf(tile[cc*16+jj][r]);
  u32 w8[8];
  #pragma unroll
  for (int p=0;p<8;p++) w8[p] = (u32)ov[2*p] | ((u32)ov[2*p+1]<<16);
  u16* dp = ht + (size_t)b*64*2048 + (size_t)r*2048 + k0 + cc*16;
  *(uint4*)dp     = make_uint4(w8[0],w8[1],w8[2],w8[3]);
  *(uint4*)(dp+8) = make_uint4(w8[4],w8[5],w8[6],w8[7]);
}

// ---------------------------------------------------------------------------
// K1: row n of A = E E^T. sign-mask (1 pos, 2 neg, 0 zero) + P=softmax(relu) bf16.
// ---------------------------------------------------------------------------
__global__ void k_P(const float* __restrict__ E, u16* __restrict__ P, u8* __restrict__ msk){
  __shared__ float Ew[16];
  __shared__ float arow[2048];
  __shared__ float red[4];
  const int t = threadIdx.x, n = blockIdx.x;
  if (t < 16) Ew[t] = E[n*16 + t];
  __syncthreads();
  float lmax = 0.f;
  for (int i=0;i<8;i++){
    int m = t + 256*i;
    const float* ep = E + m*16;
    float dot = 0.f;
    #pragma unroll
    for (int d=0; d<16; ++d) dot += Ew[d]*ep[d];
    msk[n*2048 + m] = dot > 0.f ? (u8)1 : (dot < 0.f ? (u8)2 : (u8)0);
    float ar = fmaxf(dot, 0.f);
    arow[m] = ar;
    lmax = fmaxf(lmax, ar);
  }
  for (int o=1;o<64;o<<=1) lmax = fmaxf(lmax, __shfl_xor(lmax, o));
  if ((t&63)==0) red[t>>6] = lmax;
  __syncthreads();
  float gmax = fmaxf(fmaxf(red[0],red[1]), fmaxf(red[2],red[3]));
  __syncthreads();
  float lsum = 0.f;
  for (int i=0;i<8;i++){
    int m = t + 256*i;
    float e = expf(arow[m] - gmax);
    arow[m] = e;
    lsum += e;
  }
  for (int o=1;o<64;o<<=1) lsum += __shfl_xor(lsum, o);
  if ((t&63)==0) red[t>>6] = lsum;
  __syncthreads();
  float inv = 1.f/(red[0]+red[1]+red[2]+red[3]);
  for (int i=0;i<8;i++){
    int m = t + 256*i;
    P[n*2048 + m] = f2bf(arow[m]*inv);
  }
}

// ---------------------------------------------------------------------------
// K2x: c1x[b,n,c] = sum_m P[n,m] * x[b,m,c]
// ---------------------------------------------------------------------------
__global__ void k_c1x(const u16* __restrict__ P, const float* __restrict__ x, float* __restrict__ c1x){
  const int t = threadIdx.x;
  const int r = t>>1, c = t&1;
  const int n = blockIdx.x*64 + r, b = blockIdx.y;
  const u16* pr = P + (size_t)n*2048;
  const float* xb = x + (size_t)b*2048*2 + c;
  float acc = 0.f;
  for (int m=0;m<2048;m+=4){
    acc += bf2f(pr[m+0])*xb[(m+0)*2];
    acc += bf2f(pr[m+1])*xb[(m+1)*2];
    acc += bf2f(pr[m+2])*xb[(m+2)*2];
    acc += bf2f(pr[m+3])*xb[(m+3)*2];
  }
  c1x[((size_t)b*2048 + n)*2 + c] = acc;
}

// ---------------------------------------------------------------------------
// K2: Y[b,n,d] = sum_m P[n,m] * Z[b,m,d], Z f32 [B,N,64]. 64x64 tile.
// ---------------------------------------------------------------------------
__global__ void k_conv(const u16* __restrict__ P, const float* __restrict__ Z, float* __restrict__ Y){
  __shared__ float Pt[16][68];
  __shared__ float Zt[16][68];
  const int t = threadIdx.x;
  const int tr = t>>4, tc = t&15;
  const int n0 = blockIdx.x*64, b = blockIdx.y;
  float acc[4][4] = {};
  for (int mt=0; mt<128; ++mt){
    int m0 = mt*16;
    {
      int r = t>>2, c4 = (t&3)*4;
      const u16* pp = P + (size_t)(n0+r)*2048 + m0 + c4;
      u32 p0 = *(const u32*)pp, p1v = *(const u32*)(pp+2);
      Pt[c4+0][r]=bf2f((u16)p0);  Pt[c4+1][r]=bf2f((u16)(p0>>16));
      Pt[c4+2][r]=bf2f((u16)p1v); Pt[c4+3][r]=bf2f((u16)(p1v>>16));
      int mm = t>>4, d0 = (t&15)*4;
      float4 zv = *(const float4*)&Z[((size_t)b*2048 + m0+mm)*64 + d0];
      Zt[mm][d0+0]=zv.x; Zt[mm][d0+1]=zv.y; Zt[mm][d0+2]=zv.z; Zt[mm][d0+3]=zv.w;
    }
    __syncthreads();
    #pragma unroll
    for (int mm=0; mm<16; ++mm){
      float4 a  = *(const float4*)&Pt[mm][tr*4];
      float4 bz = *(const float4*)&Zt[mm][tc*4];
      acc[0][0]+=a.x*bz.x; acc[0][1]+=a.x*bz.y; acc[0][2]+=a.x*bz.z; acc[0][3]+=a.x*bz.w;
      acc[1][0]+=a.y*bz.x; acc[1][1]+=a.y*bz.y; acc[1][2]+=a.y*bz.z; acc[1][3]+=a.y*bz.w;
      acc[2][0]+=a.z*bz.x; acc[2][1]+=a.z*bz.y; acc[2][2]+=a.z*bz.z; acc[2][3]+=a.z*bz.w;
      acc[3][0]+=a.w*bz.x; acc[3][1]+=a.w*bz.y; acc[3][2]+=a.w*bz.z; acc[3][3]+=a.w*bz.w;
    }
    __syncthreads();
  }
  #pragma unroll
  for (int i=0;i<4;i++){
    float4 v = make_float4(acc[i][0],acc[i][1],acc[i][2],acc[i][3]);
    *(float4*)&Y[((size_t)b*2048 + n0 + tr*4 + i)*64 + tc*4] = v;
  }
}

// ---------------------------------------------------------------------------
// K3: gate SAGC -> zs = z*state, rws = r. One block per node n.
// ---------------------------------------------------------------------------
__global__ void k_gate(const float* __restrict__ E, const float* __restrict__ gw, const float* __restrict__ gb,
                       const float* __restrict__ x, const float* __restrict__ state,
                       const float* __restrict__ c1x, const float* __restrict__ c1s,
                       float* __restrict__ zs, float* __restrict__ rws){
  __shared__ float Ew[16];
  __shared__ float bnv[128];
  __shared__ float Wn[2][66][64];
  __shared__ float xg4[4][2][66];
  const int t = threadIdx.x, n = blockIdx.x;
  if (t < 16) Ew[t] = E[n*16 + t];
  __syncthreads();
  if (t < 128){
    float a = 0.f;
    #pragma unroll
    for (int e=0;e<16;e++) a += Ew[e]*gb[e*128 + t];
    bnv[t] = a;
  }
  for (int half=0; half<2; ++half){
    for (int idx=t; idx<8448; idx+=256){
      int o = idx & 63, rest = idx>>6, i = rest % 66, k = rest / 66;
      float a = 0.f;
      #pragma unroll
      for (int e=0;e<16;e++) a += Ew[e]*gw[((e*2+k)*66 + i)*128 + half*64 + o];
      Wn[k][i][o] = a;
    }
    __syncthreads();
    for (int bb=0; bb<4; ++bb){
      for (int idx=t; idx<528; idx+=256){
        int bi = idx/132, rem = idx%132, k = rem/66, i = rem%66;
        int b = bb*4 + bi;
        float v;
        if (k==0) v = (i<2) ? x[((size_t)b*2048+n)*2 + i] : state[((size_t)b*2048+n)*64 + (i-2)];
        else      v = (i<2) ? c1x[((size_t)b*2048+n)*2 + i] : c1s[((size_t)b*2048+n)*64 + (i-2)];
        xg4[bi][k][i] = v;
      }
      __syncthreads();
      {
        int bi = t>>6, o = t&63, b = bb*4 + bi;
        float a = 0.f;
        #pragma unroll
        for (int k=0;k<2;k++)
          for (int i=0;i<66;i++) a += xg4[bi][k][i]*Wn[k][i][o];
        a += bnv[half*64 + o];
        float s = 1.f/(1.f + expf(-a));
        if (half==0) zs[((size_t)b*2048+n)*64 + o] = s*state[((size_t)b*2048+n)*64 + o];
        else         rws[((size_t)b*2048+n)*64 + o] = s;
      }
      __syncthreads();
    }
  }
}

// ---------------------------------------------------------------------------
// K3b: update SAGC -> hc -> h = r*state + (1-r)*hc.
// ---------------------------------------------------------------------------
__global__ void k_upd(const float* __restrict__ E, const float* __restrict__ uw, const float* __restrict__ ub,
                      const float* __restrict__ x, const float* __restrict__ state,
                      const float* __restrict__ zs, const float* __restrict__ c1x, const float* __restrict__ c2s,
                      const float* __restrict__ rws, float* __restrict__ h){
  __shared__ float Ew[16];
  __shared__ float bnu[64];
  __shared__ float Wn[2][66][64];
  __shared__ float xg4[4][2][66];
  const int t = threadIdx.x, n = blockIdx.x;
  if (t < 16) Ew[t] = E[n*16 + t];
  __syncthreads();
  if (t < 64){
    float a = 0.f;
    #pragma unroll
    for (int e=0;e<16;e++) a += Ew[e]*ub[e*64 + t];
    bnu[t] = a;
  }
  for (int idx=t; idx<8448; idx+=256){
    int o = idx & 63, rest = idx>>6, i = rest % 66, k = rest / 66;
    float a = 0.f;
    #pragma unroll
    for (int e=0;e<16;e++) a += Ew[e]*uw[((e*2+k)*66 + i)*64 + o];
    Wn[k][i][o] = a;
  }
  __syncthreads();
  for (int bb=0; bb<4; ++bb){
    for (int idx=t; idx<528; idx+=256){
      int bi = idx/132, rem = idx%132, k = rem/66, i = rem%66;
      int b = bb*4 + bi;
      float v;
      if (k==0) v = (i<2) ? x[((size_t)b*2048+n)*2 + i] : zs[((size_t)b*2048+n)*64 + (i-2)];
      else      v = (i<2) ? c1x[((size_t)b*2048+n)*2 + i] : c2s[((size_t)b*2048+n)*64 + (i-2)];
      xg4[bi][k][i] = v;
    }
    __syncthreads();
    {
      int bi = t>>6, o = t&63, b = bb*4 + bi;
      float a = 0.f;
      #pragma unroll
      for (int k=0;k<2;k++)
        for (int i=0;i<66;i++) a += xg4[bi][k][i]*Wn[k][i][o];
      float hc = tanhf(a + bnu[o]);
      float rv = rws[((size_t)b*2048+n)*64 + o];
      h[((size_t)b*2048+n)*64 + o] = rv*state[((size_t)b*2048+n)*64 + o] + (1.f - rv)*hc;
    }
    __syncthreads();
  }
}

// ---------------------------------------------------------------------------
// K5: fused degrees via MFMA. 32-row tiles. grid (64, B, 2), block 256.
// LDS: dynamic S[32][2056] bf16 (131,584 B) + static reduction scratch.
// Phase1: S = mask(HH^T) via mfma (A,B packed from f32 h)
// Phase2: L[32][2048] = S @ Wt^T via mfma, acc fully in regs (256 VGPR)
// Phase3: row softmax over k (reg + shfl + LDS cross-wave), deg -> S (bf16)
// Phase4: out[32][64] = deg @ h via mfma (B from ht)
// ---------------------------------------------------------------------------
#define SROW2 2056

__global__ void __launch_bounds__(256,1) k_deg(
    const u8* __restrict__ msk, const float* __restrict__ h,
    const u16* __restrict__ Wct, const u16* __restrict__ Wdt,
    const u16* __restrict__ ht, float* __restrict__ outc, float* __restrict__ outd){
  extern __shared__ u16 S[];
  __shared__ float redm[32][4];
  __shared__ float redsum[32][4];
  const int t = threadIdx.x;
  const int w = t >> 6, lane = t & 63;
  const int lc = lane & 15, q = lane >> 4;
  const int n0 = blockIdx.x*32, b = blockIdx.y, mask = blockIdx.z;
  const u16* Wt = mask ? Wdt : Wct;
  const u8 want = mask ? (u8)2 : (u8)1;
  const float* hb = h + (size_t)b*2048*64;
  const u16* htb = ht + (size_t)b*64*2048;

  // ---- phase 1: S[r][m] = mask ? h_{n0+r}.h_m : 0  (bf16, LDS) ----
  {
    bf16x8 Af[2][2];
    #pragma unroll
    for (int rt=0; rt<2; ++rt)
      #pragma unroll
      for (int ks=0; ks<2; ++ks)
        Af[rt][ks] = pack_bf8(&hb[(size_t)(n0 + rt*16 + lc)*64 + ks*32 + q*8]);
    for (int ct=0; ct<32; ++ct){
      const int mcol = w*512 + ct*16 + lc;
      f32x4 a0 = {0.f,0.f,0.f,0.f}, a1 = {0.f,0.f,0.f,0.f};
      #pragma unroll
      for (int ks=0; ks<2; ++ks){
        bf16x8 Bf = pack_bf8(&hb[(size_t)mcol*64 + ks*32 + q*8]);
        a0 = __builtin_amdgcn_mfma_f32_16x16x32_bf16(Af[0][ks], Bf, a0, 0,0,0);
        a1 = __builtin_amdgcn_mfma_f32_16x16x32_bf16(Af[1][ks], Bf, a1, 0,0,0);
      }
      #pragma unroll
      for (int i=0;i<4;i++){
        int r0 = q*4 + i, r1 = 16 + q*4 + i;
        S[r0*SROW2 + mcol] = (msk[(size_t)(n0+r0)*2048 + mcol]==want) ? f2bf(a0[i]) : (u16)0;
        S[r1*SROW2 + mcol] = (msk[(size_t)(n0+r1)*2048 + mcol]==want) ? f2bf(a1[i]) : (u16)0;
      }
    }
  }
  __syncthreads();

  // ---- phase 2: L = S @ W (this wave owns k-cols [w*512, w*512+512)) ----
  f32x4 acc[2][32];
  #pragma unroll
  for (int rt=0;rt<2;rt++)
    #pragma unroll
    for (int ct=0;ct<32;ct++) acc[rt][ct] = (f32x4){0.f,0.f,0.f,0.f};
  {
    const u16* wb = Wt + (size_t)(w*512 + lc)*2048 + q*8;
    for (int ks=0; ks<64; ++ks){
      const u16* sA = S + lc*SROW2 + ks*32 + q*8;
      bf16x8 A0 = *(const bf16x8*)sA;
      bf16x8 A1 = *(const bf16x8*)(sA + 16*SROW2);
      const u16* wk = wb + ks*32;
      #pragma unroll
      for (int ct=0; ct<32; ++ct){
        bf16x8 Bf = *(const bf16x8*)(wk + (size_t)ct*16*2048);
        acc[0][ct] = __builtin_amdgcn_mfma_f32_16x16x32_bf16(A0, Bf, acc[0][ct], 0,0,0);
        acc[1][ct] = __builtin_amdgcn_mfma_f32_16x16x32_bf16(A1, Bf, acc[1][ct], 0,0,0);
      }
    }
  }

  // ---- phase 3: softmax over k per row ----
  float gmax[2][4], ginv[2][4];
  #pragma unroll
  for (int rt=0; rt<2; ++rt)
    #pragma unroll
    for (int i=0;i<4;i++){
      float mx = -3.0e38f;
      #pragma unroll
      for (int ct=0; ct<32; ++ct) mx = fmaxf(mx, acc[rt][ct][i]);
      mx = fmaxf(mx, __shfl_xor(mx, 1));
      mx = fmaxf(mx, __shfl_xor(mx, 2));
      mx = fmaxf(mx, __shfl_xor(mx, 4));
      mx = fmaxf(mx, __shfl_xor(mx, 8));
      if (lc == 0) redm[rt*16 + q*4 + i][w] = mx;
    }
  __syncthreads();
  #pragma unroll
  for (int rt=0; rt<2; ++rt)
    #pragma unroll
    for (int i=0;i<4;i++){
      int r = rt*16 + q*4 + i;
      gmax[rt][i] = fmaxf(fmaxf(redm[r][0], redm[r][1]), fmaxf(redm[r][2], redm[r][3]));
    }
  #pragma unroll
  for (int rt=0; rt<2; ++rt)
    #pragma unroll
    for (int i=0;i<4;i++){
      float s = 0.f;
      #pragma unroll
      for (int ct=0; ct<32; ++ct){
        float e = __expf(acc[rt][ct][i] - gmax[rt][i]);
        acc[rt][ct][i] = e;
        s += e;
      }
      s += __shfl_xor(s, 1);
      s += __shfl_xor(s, 2);
      s += __shfl_xor(s, 4);
      s += __shfl_xor(s, 8);
      if (lc == 0) redsum[rt*16 + q*4 + i][w] = s;
    }
  __syncthreads();
  #pragma unroll
  for (int rt=0; rt<2; ++rt)
    #pragma unroll
    for (int i=0;i<4;i++){
      int r = rt*16 + q*4 + i;
      ginv[rt][i] = 1.f/(redsum[r][0]+redsum[r][1]+redsum[r][2]+redsum[r][3]);
    }
  // write deg back into S as bf16 (all waves are past phase-2 reads: two barriers above)
  #pragma unroll
  for (int rt=0; rt<2; ++rt)
    #pragma unroll
    for (int ct=0; ct<32; ++ct){
      const int col = w*512 + ct*16 + lc;
      #pragma unroll
      for (int i=0;i<4;i++)
        S[(rt*16 + q*4 + i)*SROW2 + col] = f2bf(acc[rt][ct][i]*ginv[rt][i]);
    }
  __syncthreads();

  // ---- phase 4: out = deg @ h (this wave owns d-cols [w*16, w*16+16)) ----
  f32x4 o0 = {0.f,0.f,0.f,0.f}, o1 = {0.f,0.f,0.f,0.f};
  {
    const u16* hB = htb + (size_t)(w*16 + lc)*2048 + q*8;
    for (int ks=0; ks<64; ++ks){
      const u16* sA = S + lc*SROW2 + ks*32 + q*8;
      bf16x8 A0 = *(const bf16x8*)sA;
      bf16x8 A1 = *(const bf16x8*)(sA + 16*SROW2);
      bf16x8 Bf = *(const bf16x8*)(hB + ks*32);
      o0 = __builtin_amdgcn_mfma_f32_16x16x32_bf16(A0, Bf, o0, 0,0,0);
      o1 = __builtin_amdgcn_mfma_f32_16x16x32_bf16(A1, Bf, o1, 0,0,0);
    }
  }
  float* op = (mask ? outd : outc) + (size_t)b*2048*64;
  #pragma unroll
  for (int i=0;i<4;i++){
    op[(size_t)(n0 + q*4 + i)*64 + w*16 + lc]      = o0[i];
    op[(size_t)(n0 + 16 + q*4 + i)*64 + w*16 + lc] = o1[i];
  }
}

// ---------------------------------------------------------------------------
// K6: numerator = 0.8h - 0.1 outc + 0.1 outd  -> f32 output
// ---------------------------------------------------------------------------
__global__ void k_final(const float* __restrict__ h, const float* __restrict__ outc,
                        const float* __restrict__ outd, float* __restrict__ out){
  size_t i = (size_t)blockIdx.x*256 + threadIdx.x;
  out[i] = 0.8f*h[i] - 0.1f*outc[i] + 0.1f*outd[i];
}

// ---------------------------------------------------------------------------
extern "C" void kernel_launch(void* const* d_in, const int* in_sizes, int n_in,
                              void* d_out, int out_size, void* d_ws, size_t ws_size,
                              hipStream_t stream) {
  const float* x     = (const float*)d_in[0];
  const float* state = (const float*)d_in[1];
  const float* E     = (const float*)d_in[2];
  const float* Wc    = (const float*)d_in[3];
  const float* Wd    = (const float*)d_in[4];
  const float* gw    = (const float*)d_in[5];
  const float* gb    = (const float*)d_in[6];
  const float* uw    = (const float*)d_in[7];
  const float* ub    = (const float*)d_in[8];

  // workspace layout (float units). Total 17,891,328 floats = 71.6 MB
  // (identical footprint to the round-3 layout that passed).
  float* ws  = (float*)d_ws;
  u16*   P    = (u16*)ws;                       // 2048*2048 bf16  -> 2,097,152 f
  u16*   ht   = (u16*)ws;                       // 16*64*2048 bf16 (aliases P; P dead by then)
  u8*    msk  = (u8*)(ws + 2097152);            // 2048*2048 u8    -> 1,048,576 f
  u16*   Wct  = (u16*)(ws + 3145728);           // 2048*2048 bf16  -> 2,097,152 f
  u16*   Wdt  = (u16*)(ws + 5242880);           // 2048*2048 bf16  -> 2,097,152 f
  float* c1x  = ws + 7340032;                   //    65,536 f
  float* c1s  = ws + 7405568;                   // 2,097,152 f
  float* zs   = ws + 9502720;                   // 2,097,152 f
  float* rws  = ws + 11599872;                  // 2,097,152 f
  float* c2s  = ws + 13697024;                  // 2,097,152 f
  float* h    = ws + 15794176;                  // 2,097,152 f
  float* oc   = c1s;                            // dead after k_gate
  float* od   = c2s;                            // dead after k_upd

  k_wt<<<dim3(32,32,2), 256, 0, stream>>>(Wc, Wd, Wct, Wdt);
  k_P<<<2048, 256, 0, stream>>>(E, P, msk);
  k_c1x<<<dim3(32,16), 128, 0, stream>>>(P, x, c1x);
  k_conv<<<dim3(32,16), 256, 0, stream>>>(P, state, c1s);
  k_gate<<<2048, 256, 0, stream>>>(E, gw, gb, x, state, c1x, c1s, zs, rws);
  k_conv<<<dim3(32,16), 256, 0, stream>>>(P, zs, c2s);
  k_upd<<<2048, 256, 0, stream>>>(E, uw, ub, x, state, zs, c1x, c2s, rws, h);
  k_ht<<<dim3(32,16), 256, 0, stream>>>(h, ht);

  const int deg_lds = 32*SROW2*2;   // 131,584 B dynamic
  hipFuncSetAttribute((const void*)k_deg, hipFuncAttributeMaxDynamicSharedMemorySize, deg_lds);
  k_deg<<<dim3(64,16,2), 256, deg_lds, stream>>>(msk, h, Wct, Wdt, ht, oc, od);

  k_final<<<8192, 256, 0, stream>>>(h, oc, od, (float*)d_out);
}

// Round 5
// 2899.189 us; speedup vs baseline: 2.8331x; 1.3199x over previous
//
#include <hip/hip_runtime.h>
#include <hip/hip_bf16.h>

typedef unsigned short u16;
typedef unsigned int   u32;
typedef unsigned char  u8;

typedef __attribute__((ext_vector_type(8))) short bf16x8;
typedef __attribute__((ext_vector_type(4))) float f32x4;

static __device__ __forceinline__ float bf2f(u16 u){ return __uint_as_float(((u32)u)<<16); }
static __device__ __forceinline__ u16 f2bf(float f){
  u32 u = __float_as_uint(f);
  u32 r = (u + 0x7fff + ((u>>16)&1)) >> 16;   // RNE; inputs finite
  return (u16)r;
}

// fp8 e4m3 (OCP) helpers — HW cvt, saturating via pre-clamp
static __device__ __forceinline__ u8 f2fp8(float v){
  v = fminf(440.f, fmaxf(-440.f, v));
  return (u8)(__builtin_amdgcn_cvt_pk_fp8_f32(v, 0.f, 0, false) & 0xff);
}
static __device__ __forceinline__ u32 pk4_fp8(float a, float b, float c, float d){
  int w = __builtin_amdgcn_cvt_pk_fp8_f32(a, b, 0, false);
  w = __builtin_amdgcn_cvt_pk_fp8_f32(c, d, w, true);
  return (u32)w;
}

static __device__ __forceinline__ f32x4 mfma_bf16(bf16x8 a, bf16x8 b, f32x4 c){
  return __builtin_amdgcn_mfma_f32_16x16x32_bf16(a, b, c, 0, 0, 0);
}
static __device__ __forceinline__ f32x4 mfma_fp8(long a, long b, f32x4 c){
  return __builtin_amdgcn_mfma_f32_16x16x32_fp8_fp8(a, b, c, 0, 0, 0);
}
static __device__ __forceinline__ long lo64(uint4 v){ return (long)(((unsigned long long)v.y<<32) | v.x); }
static __device__ __forceinline__ long hi64(uint4 v){ return (long)(((unsigned long long)v.w<<32) | v.z); }

// ---------------------------------------------------------------------------
// K-w8: W f32 [m][k] -> Wp fp8 [k][ fragment-major m ]: byte(k, q*512 + ksm*8 + j)
// = fp8(16 * W[ksm*32 + q*8 + j][k]).  grid (32,32,2), block 256.
// ---------------------------------------------------------------------------
__global__ void k_w8(const float* __restrict__ Wc, const float* __restrict__ Wd,
                     u8* __restrict__ Wc8, u8* __restrict__ Wd8){
  __shared__ float tile[64][65];
  const float* src = blockIdx.z ? Wd : Wc;
  u8* dst = blockIdx.z ? Wd8 : Wc8;
  const int m0 = blockIdx.x*64, k0 = blockIdx.y*64;
  const int t = threadIdx.x, r = t & 63, cc = t >> 6;
  #pragma unroll
  for (int j=0;j<4;j++){
    float4 v = *(const float4*)&src[(size_t)(m0+r)*2048 + k0 + cc*16 + j*4];
    tile[r][cc*16+j*4+0]=v.x; tile[r][cc*16+j*4+1]=v.y;
    tile[r][cc*16+j*4+2]=v.z; tile[r][cc*16+j*4+3]=v.w;
  }
  __syncthreads();
  u32 f0 = pk4_fp8(16.f*tile[cc*16+ 0][r], 16.f*tile[cc*16+ 1][r], 16.f*tile[cc*16+ 2][r], 16.f*tile[cc*16+ 3][r]);
  u32 f1 = pk4_fp8(16.f*tile[cc*16+ 4][r], 16.f*tile[cc*16+ 5][r], 16.f*tile[cc*16+ 6][r], 16.f*tile[cc*16+ 7][r]);
  u32 f2 = pk4_fp8(16.f*tile[cc*16+ 8][r], 16.f*tile[cc*16+ 9][r], 16.f*tile[cc*16+10][r], 16.f*tile[cc*16+11][r]);
  u32 f3 = pk4_fp8(16.f*tile[cc*16+12][r], 16.f*tile[cc*16+13][r], 16.f*tile[cc*16+14][r], 16.f*tile[cc*16+15][r]);
  int mbase = m0 + cc*16;
  int ksm = mbase >> 5, qa = (mbase >> 3) & 3;
  u8* dp = dst + (size_t)(k0+r)*2048;
  *(uint2*)(dp + qa*512     + ksm*8) = make_uint2(f0, f1);
  *(uint2*)(dp + (qa+1)*512 + ksm*8) = make_uint2(f2, f3);
}

// ---------------------------------------------------------------------------
// K-hcvt: h f32 [b][m][d] -> hb16 bf16 [b][m][d] (row-major) and
// ht8 fp8 [b][d][ fragment-major m ].  grid (32,16), block 256.
// ---------------------------------------------------------------------------
__global__ void k_hcvt(const float* __restrict__ h, u16* __restrict__ hb16, u8* __restrict__ ht8){
  __shared__ float tile[64][65];
  const int k0 = blockIdx.x*64, b = blockIdx.y;
  const int t = threadIdx.x, r = t & 63, cc = t >> 6;
  const float* src = h + ((size_t)b*2048 + k0)*64;
  u32 hw[8];
  #pragma unroll
  for (int j=0;j<4;j++){
    float4 v = *(const float4*)&src[(size_t)r*64 + cc*16 + j*4];
    tile[r][cc*16+j*4+0]=v.x; tile[r][cc*16+j*4+1]=v.y;
    tile[r][cc*16+j*4+2]=v.z; tile[r][cc*16+j*4+3]=v.w;
    hw[2*j]   = (u32)f2bf(v.x) | ((u32)f2bf(v.y)<<16);
    hw[2*j+1] = (u32)f2bf(v.z) | ((u32)f2bf(v.w)<<16);
  }
  u16* hp = hb16 + (((size_t)b*2048 + k0 + r)*64 + cc*16);
  *(uint4*)hp     = make_uint4(hw[0],hw[1],hw[2],hw[3]);
  *(uint4*)(hp+8) = make_uint4(hw[4],hw[5],hw[6],hw[7]);
  __syncthreads();
  u32 f0 = pk4_fp8(tile[cc*16+ 0][r], tile[cc*16+ 1][r], tile[cc*16+ 2][r], tile[cc*16+ 3][r]);
  u32 f1 = pk4_fp8(tile[cc*16+ 4][r], tile[cc*16+ 5][r], tile[cc*16+ 6][r], tile[cc*16+ 7][r]);
  u32 f2 = pk4_fp8(tile[cc*16+ 8][r], tile[cc*16+ 9][r], tile[cc*16+10][r], tile[cc*16+11][r]);
  u32 f3 = pk4_fp8(tile[cc*16+12][r], tile[cc*16+13][r], tile[cc*16+14][r], tile[cc*16+15][r]);
  int mbase = k0 + cc*16;
  int ksm = mbase >> 5, qa = (mbase >> 3) & 3;
  u8* dp = ht8 + ((size_t)b*64 + r)*2048;
  *(uint2*)(dp + qa*512     + ksm*8) = make_uint2(f0, f1);
  *(uint2*)(dp + (qa+1)*512 + ksm*8) = make_uint2(f2, f3);
}

// ---------------------------------------------------------------------------
// K1: row n of A = E E^T. sign-mask (1 pos, 2 neg, 0 zero) + P=softmax(relu) bf16.
// ---------------------------------------------------------------------------
__global__ void k_P(const float* __restrict__ E, u16* __restrict__ P, u8* __restrict__ msk){
  __shared__ float Ew[16];
  __shared__ float arow[2048];
  __shared__ float red[4];
  const int t = threadIdx.x, n = blockIdx.x;
  if (t < 16) Ew[t] = E[n*16 + t];
  __syncthreads();
  float lmax = 0.f;
  for (int i=0;i<8;i++){
    int m = t + 256*i;
    const float* ep = E + m*16;
    float dot = 0.f;
    #pragma unroll
    for (int d=0; d<16; ++d) dot += Ew[d]*ep[d];
    msk[n*2048 + m] = dot > 0.f ? (u8)1 : (dot < 0.f ? (u8)2 : (u8)0);
    float ar = fmaxf(dot, 0.f);
    arow[m] = ar;
    lmax = fmaxf(lmax, ar);
  }
  for (int o=1;o<64;o<<=1) lmax = fmaxf(lmax, __shfl_xor(lmax, o));
  if ((t&63)==0) red[t>>6] = lmax;
  __syncthreads();
  float gmax = fmaxf(fmaxf(red[0],red[1]), fmaxf(red[2],red[3]));
  __syncthreads();
  float lsum = 0.f;
  for (int i=0;i<8;i++){
    int m = t + 256*i;
    float e = expf(arow[m] - gmax);
    arow[m] = e;
    lsum += e;
  }
  for (int o=1;o<64;o<<=1) lsum += __shfl_xor(lsum, o);
  if ((t&63)==0) red[t>>6] = lsum;
  __syncthreads();
  float inv = 1.f/(red[0]+red[1]+red[2]+red[3]);
  for (int i=0;i<8;i++){
    int m = t + 256*i;
    P[n*2048 + m] = f2bf(arow[m]*inv);
  }
}

// ---------------------------------------------------------------------------
// K2x: c1x[b,n,c] = sum_m P[n,m] * x[b,m,c]
// ---------------------------------------------------------------------------
__global__ void k_c1x(const u16* __restrict__ P, const float* __restrict__ x, float* __restrict__ c1x){
  const int t = threadIdx.x;
  const int r = t>>1, c = t&1;
  const int n = blockIdx.x*64 + r, b = blockIdx.y;
  const u16* pr = P + (size_t)n*2048;
  const float* xb = x + (size_t)b*2048*2 + c;
  float acc = 0.f;
  for (int m=0;m<2048;m+=4){
    acc += bf2f(pr[m+0])*xb[(m+0)*2];
    acc += bf2f(pr[m+1])*xb[(m+1)*2];
    acc += bf2f(pr[m+2])*xb[(m+2)*2];
    acc += bf2f(pr[m+3])*xb[(m+3)*2];
  }
  c1x[((size_t)b*2048 + n)*2 + c] = acc;
}

// ---------------------------------------------------------------------------
// K2: Y[b,n,d] = sum_m P[n,m] * Z[b,m,d], Z f32 [B,N,64]. 64x64 tile.
// ---------------------------------------------------------------------------
__global__ void k_conv(const u16* __restrict__ P, const float* __restrict__ Z, float* __restrict__ Y){
  __shared__ float Pt[16][68];
  __shared__ float Zt[16][68];
  const int t = threadIdx.x;
  const int tr = t>>4, tc = t&15;
  const int n0 = blockIdx.x*64, b = blockIdx.y;
  float acc[4][4] = {};
  for (int mt=0; mt<128; ++mt){
    int m0 = mt*16;
    {
      int r = t>>2, c4 = (t&3)*4;
      const u16* pp = P + (size_t)(n0+r)*2048 + m0 + c4;
      u32 p0 = *(const u32*)pp, p1v = *(const u32*)(pp+2);
      Pt[c4+0][r]=bf2f((u16)p0);  Pt[c4+1][r]=bf2f((u16)(p0>>16));
      Pt[c4+2][r]=bf2f((u16)p1v); Pt[c4+3][r]=bf2f((u16)(p1v>>16));
      int mm = t>>4, d0 = (t&15)*4;
      float4 zv = *(const float4*)&Z[((size_t)b*2048 + m0+mm)*64 + d0];
      Zt[mm][d0+0]=zv.x; Zt[mm][d0+1]=zv.y; Zt[mm][d0+2]=zv.z; Zt[mm][d0+3]=zv.w;
    }
    __syncthreads();
    #pragma unroll
    for (int mm=0; mm<16; ++mm){
      float4 a  = *(const float4*)&Pt[mm][tr*4];
      float4 bz = *(const float4*)&Zt[mm][tc*4];
      acc[0][0]+=a.x*bz.x; acc[0][1]+=a.x*bz.y; acc[0][2]+=a.x*bz.z; acc[0][3]+=a.x*bz.w;
      acc[1][0]+=a.y*bz.x; acc[1][1]+=a.y*bz.y; acc[1][2]+=a.y*bz.z; acc[1][3]+=a.y*bz.w;
      acc[2][0]+=a.z*bz.x; acc[2][1]+=a.z*bz.y; acc[2][2]+=a.z*bz.z; acc[2][3]+=a.z*bz.w;
      acc[3][0]+=a.w*bz.x; acc[3][1]+=a.w*bz.y; acc[3][2]+=a.w*bz.z; acc[3][3]+=a.w*bz.w;
    }
    __syncthreads();
  }
  #pragma unroll
  for (int i=0;i<4;i++){
    float4 v = make_float4(acc[i][0],acc[i][1],acc[i][2],acc[i][3]);
    *(float4*)&Y[((size_t)b*2048 + n0 + tr*4 + i)*64 + tc*4] = v;
  }
}

// ---------------------------------------------------------------------------
// K3: gate SAGC -> zs = z*state, rws = r. One block per node n.
// ---------------------------------------------------------------------------
__global__ void k_gate(const float* __restrict__ E, const float* __restrict__ gw, const float* __restrict__ gb,
                       const float* __restrict__ x, const float* __restrict__ state,
                       const float* __restrict__ c1x, const float* __restrict__ c1s,
                       float* __restrict__ zs, float* __restrict__ rws){
  __shared__ float Ew[16];
  __shared__ float bnv[128];
  __shared__ float Wn[2][66][64];
  __shared__ float xg4[4][2][66];
  const int t = threadIdx.x, n = blockIdx.x;
  if (t < 16) Ew[t] = E[n*16 + t];
  __syncthreads();
  if (t < 128){
    float a = 0.f;
    #pragma unroll
    for (int e=0;e<16;e++) a += Ew[e]*gb[e*128 + t];
    bnv[t] = a;
  }
  for (int half=0; half<2; ++half){
    for (int idx=t; idx<8448; idx+=256){
      int o = idx & 63, rest = idx>>6, i = rest % 66, k = rest / 66;
      float a = 0.f;
      #pragma unroll
      for (int e=0;e<16;e++) a += Ew[e]*gw[((e*2+k)*66 + i)*128 + half*64 + o];
      Wn[k][i][o] = a;
    }
    __syncthreads();
    for (int bb=0; bb<4; ++bb){
      for (int idx=t; idx<528; idx+=256){
        int bi = idx/132, rem = idx%132, k = rem/66, i = rem%66;
        int b = bb*4 + bi;
        float v;
        if (k==0) v = (i<2) ? x[((size_t)b*2048+n)*2 + i] : state[((size_t)b*2048+n)*64 + (i-2)];
        else      v = (i<2) ? c1x[((size_t)b*2048+n)*2 + i] : c1s[((size_t)b*2048+n)*64 + (i-2)];
        xg4[bi][k][i] = v;
      }
      __syncthreads();
      {
        int bi = t>>6, o = t&63, b = bb*4 + bi;
        float a = 0.f;
        #pragma unroll
        for (int k=0;k<2;k++)
          for (int i=0;i<66;i++) a += xg4[bi][k][i]*Wn[k][i][o];
        a += bnv[half*64 + o];
        float s = 1.f/(1.f + expf(-a));
        if (half==0) zs[((size_t)b*2048+n)*64 + o] = s*state[((size_t)b*2048+n)*64 + o];
        else         rws[((size_t)b*2048+n)*64 + o] = s;
      }
      __syncthreads();
    }
  }
}

// ---------------------------------------------------------------------------
// K3b: update SAGC -> hc -> h = r*state + (1-r)*hc.
// ---------------------------------------------------------------------------
__global__ void k_upd(const float* __restrict__ E, const float* __restrict__ uw, const float* __restrict__ ub,
                      const float* __restrict__ x, const float* __restrict__ state,
                      const float* __restrict__ zs, const float* __restrict__ c1x, const float* __restrict__ c2s,
                      const float* __restrict__ rws, float* __restrict__ h){
  __shared__ float Ew[16];
  __shared__ float bnu[64];
  __shared__ float Wn[2][66][64];
  __shared__ float xg4[4][2][66];
  const int t = threadIdx.x, n = blockIdx.x;
  if (t < 16) Ew[t] = E[n*16 + t];
  __syncthreads();
  if (t < 64){
    float a = 0.f;
    #pragma unroll
    for (int e=0;e<16;e++) a += Ew[e]*ub[e*64 + t];
    bnu[t] = a;
  }
  for (int idx=t; idx<8448; idx+=256){
    int o = idx & 63, rest = idx>>6, i = rest % 66, k = rest / 66;
    float a = 0.f;
    #pragma unroll
    for (int e=0;e<16;e++) a += Ew[e]*uw[((e*2+k)*66 + i)*64 + o];
    Wn[k][i][o] = a;
  }
  __syncthreads();
  for (int bb=0; bb<4; ++bb){
    for (int idx=t; idx<528; idx+=256){
      int bi = idx/132, rem = idx%132, k = rem/66, i = rem%66;
      int b = bb*4 + bi;
      float v;
      if (k==0) v = (i<2) ? x[((size_t)b*2048+n)*2 + i] : zs[((size_t)b*2048+n)*64 + (i-2)];
      else      v = (i<2) ? c1x[((size_t)b*2048+n)*2 + i] : c2s[((size_t)b*2048+n)*64 + (i-2)];
      xg4[bi][k][i] = v;
    }
    __syncthreads();
    {
      int bi = t>>6, o = t&63, b = bb*4 + bi;
      float a = 0.f;
      #pragma unroll
      for (int k=0;k<2;k++)
        for (int i=0;i<66;i++) a += xg4[bi][k][i]*Wn[k][i][o];
      float hc = tanhf(a + bnu[o]);
      float rv = rws[((size_t)b*2048+n)*64 + o];
      h[((size_t)b*2048+n)*64 + o] = rv*state[((size_t)b*2048+n)*64 + o] + (1.f - rv)*hc;
    }
    __syncthreads();
  }
}

// ---------------------------------------------------------------------------
// K5: fused degrees, fp8 MFMA. 32-row tiles, 512 threads (8 waves), 2 waves/SIMD.
// grid (64, 16, 2). LDS: S fp8 [32][2056] dynamic (65,792 B) + 2 KB static.
// Scaling: S stores S/8; W stores 16W -> logits = 0.5*acc; deg stored *256.
// ---------------------------------------------------------------------------
#define SROW8 2056

__global__ void __launch_bounds__(512,2) k_deg(
    const u8* __restrict__ msk, const u16* __restrict__ hb16,
    const u8* __restrict__ Wc8, const u8* __restrict__ Wd8,
    const u8* __restrict__ ht8, float* __restrict__ outc, float* __restrict__ outd){
  extern __shared__ u8 S[];
  __shared__ float redm[32][8];
  __shared__ float redsum[32][8];
  const int t = threadIdx.x;
  const int w = t >> 6, lane = t & 63, lc = lane & 15, q = lane >> 4;
  const int n0 = blockIdx.x*32, b = blockIdx.y, mask = blockIdx.z;
  const u8* W8 = mask ? Wd8 : Wc8;
  const u8 want = mask ? (u8)2 : (u8)1;
  const u16* hbb = hb16 + (size_t)b*2048*64;
  const u8* htb = ht8 + (size_t)b*64*2048;

  // ---- phase 1: S[r][m] = fp8( (mask ? h_n.h_m : 0) / 8 ) ----
  {
    bf16x8 A[2][2];
    #pragma unroll
    for (int rt=0; rt<2; ++rt)
      #pragma unroll
      for (int ks=0; ks<2; ++ks)
        A[rt][ks] = *(const bf16x8*)&hbb[(size_t)(n0 + rt*16 + lc)*64 + ks*32 + q*8];
    for (int ct=0; ct<16; ++ct){
      const int mcol = w*256 + ct*16 + lc;
      bf16x8 B0 = *(const bf16x8*)&hbb[(size_t)mcol*64 + q*8];
      bf16x8 B1 = *(const bf16x8*)&hbb[(size_t)mcol*64 + 32 + q*8];
      f32x4 a0 = {0.f,0.f,0.f,0.f}, a1 = {0.f,0.f,0.f,0.f};
      a0 = mfma_bf16(A[0][0], B0, a0); a0 = mfma_bf16(A[0][1], B1, a0);
      a1 = mfma_bf16(A[1][0], B0, a1); a1 = mfma_bf16(A[1][1], B1, a1);
      #pragma unroll
      for (int i=0;i<4;i++){
        int r0 = q*4 + i, r1 = 16 + q*4 + i;
        float v0 = (msk[(size_t)(n0+r0)*2048 + mcol]==want) ? a0[i]*0.125f : 0.f;
        float v1 = (msk[(size_t)(n0+r1)*2048 + mcol]==want) ? a1[i]*0.125f : 0.f;
        S[r0*SROW8 + mcol] = f2fp8(v0);
        S[r1*SROW8 + mcol] = f2fp8(v1);
      }
    }
  }
  __syncthreads();

  // ---- phase 2: logits = S @ W ; wave owns k-cols [w*256, w*256+256) ----
  f32x4 acc0[16], acc1[16];
  #pragma unroll
  for (int ct=0;ct<16;ct++){ acc0[ct] = (f32x4){0.f,0.f,0.f,0.f}; acc1[ct] = (f32x4){0.f,0.f,0.f,0.f}; }
  {
    const u8* wbase = W8 + (size_t)(w*256 + lc)*2048 + q*512;
    const u8* sp0 = S + lc*SROW8 + q*8;
    const u8* sp1 = sp0 + 16*SROW8;
    #pragma unroll 1
    for (int k8=0; k8<32; ++k8){
      long a0e = *(const long*)(sp0 + k8*64);
      long a0o = *(const long*)(sp0 + k8*64 + 32);
      long a1e = *(const long*)(sp1 + k8*64);
      long a1o = *(const long*)(sp1 + k8*64 + 32);
      uint4 bv[16];
      #pragma unroll
      for (int ct=0; ct<16; ++ct)
        bv[ct] = *(const uint4*)(wbase + (size_t)ct*16*2048 + k8*16);
      #pragma unroll
      for (int ct=0; ct<16; ++ct){
        long be = lo64(bv[ct]), bo = hi64(bv[ct]);
        acc0[ct] = mfma_fp8(a0e, be, acc0[ct]);
        acc1[ct] = mfma_fp8(a1e, be, acc1[ct]);
        acc0[ct] = mfma_fp8(a0o, bo, acc0[ct]);
        acc1[ct] = mfma_fp8(a1o, bo, acc1[ct]);
      }
    }
  }

  // ---- phase 3: row softmax over k (true logits = 0.5*acc) ----
  float gmax0[4], gmax1[4], gsc0[4], gsc1[4];
  #pragma unroll
  for (int i=0;i<4;i++){
    float mx0 = acc0[0][i], mx1 = acc1[0][i];
    #pragma unroll
    for (int ct=1; ct<16; ++ct){ mx0 = fmaxf(mx0, acc0[ct][i]); mx1 = fmaxf(mx1, acc1[ct][i]); }
    mx0 = fmaxf(mx0, __shfl_xor(mx0, 1)); mx1 = fmaxf(mx1, __shfl_xor(mx1, 1));
    mx0 = fmaxf(mx0, __shfl_xor(mx0, 2)); mx1 = fmaxf(mx1, __shfl_xor(mx1, 2));
    mx0 = fmaxf(mx0, __shfl_xor(mx0, 4)); mx1 = fmaxf(mx1, __shfl_xor(mx1, 4));
    mx0 = fmaxf(mx0, __shfl_xor(mx0, 8)); mx1 = fmaxf(mx1, __shfl_xor(mx1, 8));
    if (lc == 0){ redm[q*4+i][w] = mx0; redm[16+q*4+i][w] = mx1; }
  }
  __syncthreads();
  #pragma unroll
  for (int i=0;i<4;i++){
    float m0 = redm[q*4+i][0], m1 = redm[16+q*4+i][0];
    #pragma unroll
    for (int j=1;j<8;j++){ m0 = fmaxf(m0, redm[q*4+i][j]); m1 = fmaxf(m1, redm[16+q*4+i][j]); }
    gmax0[i] = m0; gmax1[i] = m1;
  }
  #pragma unroll
  for (int i=0;i<4;i++){
    float s0 = 0.f, s1 = 0.f;
    #pragma unroll
    for (int ct=0; ct<16; ++ct){
      float e0 = __expf(0.5f*(acc0[ct][i] - gmax0[i]));
      float e1 = __expf(0.5f*(acc1[ct][i] - gmax1[i]));
      acc0[ct][i] = e0; acc1[ct][i] = e1;
      s0 += e0; s1 += e1;
    }
    s0 += __shfl_xor(s0, 1); s1 += __shfl_xor(s1, 1);
    s0 += __shfl_xor(s0, 2); s1 += __shfl_xor(s1, 2);
    s0 += __shfl_xor(s0, 4); s1 += __shfl_xor(s1, 4);
    s0 += __shfl_xor(s0, 8); s1 += __shfl_xor(s1, 8);
    if (lc == 0){ redsum[q*4+i][w] = s0; redsum[16+q*4+i][w] = s1; }
  }
  __syncthreads();
  #pragma unroll
  for (int i=0;i<4;i++){
    float s0 = 0.f, s1 = 0.f;
    #pragma unroll
    for (int j=0;j<8;j++){ s0 += redsum[q*4+i][j]; s1 += redsum[16+q*4+i][j]; }
    gsc0[i] = 256.f/s0; gsc1[i] = 256.f/s1;
  }
  // writeback deg*256 as fp8 (phase-2 S reads all completed before the barriers above)
  #pragma unroll
  for (int ct=0; ct<16; ++ct){
    const int col = w*256 + ct*16 + lc;
    #pragma unroll
    for (int i=0;i<4;i++){
      S[(q*4+i)*SROW8 + col]      = f2fp8(acc0[ct][i]*gsc0[i]);
      S[(16+q*4+i)*SROW8 + col]   = f2fp8(acc1[ct][i]*gsc1[i]);
    }
  }
  __syncthreads();

  // ---- phase 4: out = (deg*256) @ h / 256 ; wave (rt=w>>2, dt=w&3) ----
  {
    const int rt4 = w >> 2, dt = w & 3;
    f32x4 o = {0.f,0.f,0.f,0.f};
    const u8* abase = S + (size_t)(rt4*16 + lc)*SROW8 + q*8;
    const u8* bbase = htb + (size_t)(dt*16 + lc)*2048 + q*512;
    #pragma unroll 1
    for (int k8=0; k8<32; ++k8){
      long ae = *(const long*)(abase + k8*64);
      long ao = *(const long*)(abase + k8*64 + 32);
      uint4 bv = *(const uint4*)(bbase + k8*16);
      o = mfma_fp8(ae, lo64(bv), o);
      o = mfma_fp8(ao, hi64(bv), o);
    }
    float* op = (mask ? outd : outc) + (size_t)b*2048*64;
    #pragma unroll
    for (int i=0;i<4;i++)
      op[(size_t)(n0 + rt4*16 + q*4 + i)*64 + dt*16 + lc] = o[i]*(1.f/256.f);
  }
}

// ---------------------------------------------------------------------------
// K6: numerator = 0.8h - 0.1 outc + 0.1 outd  -> f32 output
// ---------------------------------------------------------------------------
__global__ void k_final(const float* __restrict__ h, const float* __restrict__ outc,
                        const float* __restrict__ outd, float* __restrict__ out){
  size_t i = (size_t)blockIdx.x*256 + threadIdx.x;
  out[i] = 0.8f*h[i] - 0.1f*outc[i] + 0.1f*outd[i];
}

// ---------------------------------------------------------------------------
extern "C" void kernel_launch(void* const* d_in, const int* in_sizes, int n_in,
                              void* d_out, int out_size, void* d_ws, size_t ws_size,
                              hipStream_t stream) {
  const float* x     = (const float*)d_in[0];
  const float* state = (const float*)d_in[1];
  const float* E     = (const float*)d_in[2];
  const float* Wc    = (const float*)d_in[3];
  const float* Wd    = (const float*)d_in[4];
  const float* gw    = (const float*)d_in[5];
  const float* gb    = (const float*)d_in[6];
  const float* uw    = (const float*)d_in[7];
  const float* ub    = (const float*)d_in[8];

  // workspace layout (bytes). Total 69,468,160 B = 66.3 MB (round-3/4 used 71.6 MB OK).
  char* base = (char*)d_ws;
  u16*   P    = (u16*)(base + 0);           //  8,388,608
  u8*    msk  = (u8*) (base + 8388608);     //  4,194,304
  u8*    Wc8  = (u8*) (base + 12582912);    //  4,194,304
  u8*    Wd8  = (u8*) (base + 16777216);    //  4,194,304
  u16*   hb16 = (u16*)(base + 20971520);    //  4,194,304
  u8*    ht8  = (u8*) (base + 25165824);    //  2,097,152
  float* c1x  = (float*)(base + 27262976);  //    262,144
  float* c1s  = (float*)(base + 27525120);  //  8,388,608
  float* zs   = (float*)(base + 35913728);  //  8,388,608
  float* rws  = (float*)(base + 44302336);  //  8,388,608
  float* c2s  = (float*)(base + 52690944);  //  8,388,608
  float* h    = (float*)(base + 61079552);  //  8,388,608
  float* oc   = c1s;                        // dead after k_gate
  float* od   = c2s;                        // dead after k_upd

  k_w8<<<dim3(32,32,2), 256, 0, stream>>>(Wc, Wd, Wc8, Wd8);
  k_P<<<2048, 256, 0, stream>>>(E, P, msk);
  k_c1x<<<dim3(32,16), 128, 0, stream>>>(P, x, c1x);
  k_conv<<<dim3(32,16), 256, 0, stream>>>(P, state, c1s);
  k_gate<<<2048, 256, 0, stream>>>(E, gw, gb, x, state, c1x, c1s, zs, rws);
  k_conv<<<dim3(32,16), 256, 0, stream>>>(P, zs, c2s);
  k_upd<<<2048, 256, 0, stream>>>(E, uw, ub, x, state, zs, c1x, c2s, rws, h);
  k_hcvt<<<dim3(32,16), 256, 0, stream>>>(h, hb16, ht8);

  const int deg_lds = 32*SROW8;   // 65,792 B dynamic
  hipFuncSetAttribute((const void*)k_deg, hipFuncAttributeMaxDynamicSharedMemorySize, deg_lds);
  k_deg<<<dim3(64,16,2), 512, deg_lds, stream>>>(msk, hb16, Wc8, Wd8, ht8, oc, od);

  k_final<<<8192, 256, 0, stream>>>(h, oc, od, (float*)d_out);
}

// Round 6
// 2320.716 us; speedup vs baseline: 3.5393x; 1.2493x over previous
//
#include <hip/hip_runtime.h>
#include <hip/hip_bf16.h>

typedef unsigned short u16;
typedef unsigned int   u32;
typedef unsigned char  u8;

typedef __attribute__((ext_vector_type(8))) short bf16x8;
typedef __attribute__((ext_vector_type(4))) float f32x4;

static __device__ __forceinline__ float bf2f(u16 u){ return __uint_as_float(((u32)u)<<16); }
static __device__ __forceinline__ u16 f2bf(float f){
  u32 u = __float_as_uint(f);
  u32 r = (u + 0x7fff + ((u>>16)&1)) >> 16;   // RNE; inputs finite
  return (u16)r;
}

// fp8 e4m3 (OCP) helpers — HW cvt, saturating via pre-clamp
static __device__ __forceinline__ u8 f2fp8(float v){
  v = fminf(440.f, fmaxf(-440.f, v));
  return (u8)(__builtin_amdgcn_cvt_pk_fp8_f32(v, 0.f, 0, false) & 0xff);
}
static __device__ __forceinline__ u32 pk4_fp8(float a, float b, float c, float d){
  int w = __builtin_amdgcn_cvt_pk_fp8_f32(a, b, 0, false);
  w = __builtin_amdgcn_cvt_pk_fp8_f32(c, d, w, true);
  return (u32)w;
}

static __device__ __forceinline__ f32x4 mfma_bf16(bf16x8 a, bf16x8 b, f32x4 c){
  return __builtin_amdgcn_mfma_f32_16x16x32_bf16(a, b, c, 0, 0, 0);
}
static __device__ __forceinline__ f32x4 mfma_fp8(long a, long b, f32x4 c){
  return __builtin_amdgcn_mfma_f32_16x16x32_fp8_fp8(a, b, c, 0, 0, 0);
}
static __device__ __forceinline__ long lo64(uint4 v){ return (long)(((unsigned long long)v.y<<32) | v.x); }
static __device__ __forceinline__ long hi64(uint4 v){ return (long)(((unsigned long long)v.w<<32) | v.z); }

// ---------------------------------------------------------------------------
// K-w8: W f32 [m][k] -> fragment-major fp8:
// byte[ ((pt*128 + ctg)*64 + q*16 + lc)*16 + half*8 + j ] = fp8(16*W[m][k])
// with m = pt*64 + half*32 + q*8 + j,  k = ctg*16 + lc.
// One dwordx4 per wave-lane then covers a contiguous 1 KB block.
// grid (32,32,2), block 256.
// ---------------------------------------------------------------------------
__global__ void k_w8(const float* __restrict__ Wc, const float* __restrict__ Wd,
                     u8* __restrict__ Wc8, u8* __restrict__ Wd8){
  __shared__ float tile[64][65];
  const float* src = blockIdx.z ? Wd : Wc;
  u8* dst = blockIdx.z ? Wd8 : Wc8;
  const int m0 = blockIdx.x*64, k0 = blockIdx.y*64;
  const int t = threadIdx.x, r = t & 63, cc = t >> 6;
  #pragma unroll
  for (int j=0;j<4;j++){
    float4 v = *(const float4*)&src[(size_t)(m0+r)*2048 + k0 + cc*16 + j*4];
    tile[r][cc*16+j*4+0]=v.x; tile[r][cc*16+j*4+1]=v.y;
    tile[r][cc*16+j*4+2]=v.z; tile[r][cc*16+j*4+3]=v.w;
  }
  __syncthreads();
  u32 f0 = pk4_fp8(16.f*tile[cc*16+ 0][r], 16.f*tile[cc*16+ 1][r], 16.f*tile[cc*16+ 2][r], 16.f*tile[cc*16+ 3][r]);
  u32 f1 = pk4_fp8(16.f*tile[cc*16+ 4][r], 16.f*tile[cc*16+ 5][r], 16.f*tile[cc*16+ 6][r], 16.f*tile[cc*16+ 7][r]);
  u32 f2 = pk4_fp8(16.f*tile[cc*16+ 8][r], 16.f*tile[cc*16+ 9][r], 16.f*tile[cc*16+10][r], 16.f*tile[cc*16+11][r]);
  u32 f3 = pk4_fp8(16.f*tile[cc*16+12][r], 16.f*tile[cc*16+13][r], 16.f*tile[cc*16+14][r], 16.f*tile[cc*16+15][r]);
  const int k = k0 + r, mbase = m0 + cc*16;
  const int pt = mbase >> 6, half = (mbase >> 5) & 1, q0 = (mbase >> 3) & 3;
  const int ctg = k >> 4, lcv = k & 15;
  u8* dbase = dst + (size_t)((pt*128 + ctg)*64)*16 + half*8;
  *(uint2*)(dbase + (q0*16 + lcv)*16)     = make_uint2(f0, f1);
  *(uint2*)(dbase + ((q0+1)*16 + lcv)*16) = make_uint2(f2, f3);
}

// ---------------------------------------------------------------------------
// K-hcvt: from h f32 [b][m][64] produce:
//  hb16: bf16 row-major [b][m][64]                       (phase-1 A operand)
//  hfm : bf16 fragment-major [b][ks(2)][ctg(128)][lane][16B] (phase-1 B operand)
//        value = bf16(h[b][ctg*16+lc][ks*32 + q*8 + j])
//  ht8p: fp8 fragment-major [b][pt(32)*4+ctg(4)][lane][16B]  (phase-4 B operand)
//        byte half*8+j = fp8(h[b][pt*64+half*32+q*8+j][ctg*16+lc])
// grid (32,16), block 256.
// ---------------------------------------------------------------------------
__global__ void k_hcvt(const float* __restrict__ h, u16* __restrict__ hb16,
                       u8* __restrict__ ht8p, u16* __restrict__ hfm){
  __shared__ float tile[64][65];
  const int k0 = blockIdx.x*64, b = blockIdx.y;
  const int t = threadIdx.x, r = t & 63, cc = t >> 6;
  const float* src = h + ((size_t)b*2048 + k0)*64;
  u32 hw[8];
  #pragma unroll
  for (int j=0;j<4;j++){
    float4 v = *(const float4*)&src[(size_t)r*64 + cc*16 + j*4];
    tile[r][cc*16+j*4+0]=v.x; tile[r][cc*16+j*4+1]=v.y;
    tile[r][cc*16+j*4+2]=v.z; tile[r][cc*16+j*4+3]=v.w;
    hw[2*j]   = (u32)f2bf(v.x) | ((u32)f2bf(v.y)<<16);
    hw[2*j+1] = (u32)f2bf(v.z) | ((u32)f2bf(v.w)<<16);
  }
  u16* hp = hb16 + (((size_t)b*2048 + k0 + r)*64 + cc*16);
  *(uint4*)hp     = make_uint4(hw[0],hw[1],hw[2],hw[3]);
  *(uint4*)(hp+8) = make_uint4(hw[4],hw[5],hw[6],hw[7]);
  __syncthreads();
  // ---- ht8p: d = r, m = k0 + cc*16 + jj ----
  {
    u32 f0 = pk4_fp8(tile[cc*16+ 0][r], tile[cc*16+ 1][r], tile[cc*16+ 2][r], tile[cc*16+ 3][r]);
    u32 f1 = pk4_fp8(tile[cc*16+ 4][r], tile[cc*16+ 5][r], tile[cc*16+ 6][r], tile[cc*16+ 7][r]);
    u32 f2 = pk4_fp8(tile[cc*16+ 8][r], tile[cc*16+ 9][r], tile[cc*16+10][r], tile[cc*16+11][r]);
    u32 f3 = pk4_fp8(tile[cc*16+12][r], tile[cc*16+13][r], tile[cc*16+14][r], tile[cc*16+15][r]);
    const int pt = k0 >> 6, half = cc >> 1, q0 = (cc & 1)*2;
    const int ctg = r >> 4, lcv = r & 15;
    u8* dbase = ht8p + (size_t)b*131072 + (size_t)((pt*4 + ctg)*64)*16 + half*8;
    *(uint2*)(dbase + (q0*16 + lcv)*16)     = make_uint2(f0, f1);
    *(uint2*)(dbase + ((q0+1)*16 + lcv)*16) = make_uint2(f2, f3);
  }
  // ---- hfm: col = k0 + r; thread cc covers (ks = cc>>1, q = (cc&1)*2 + {0,1}) ----
  {
    const int col = k0 + r, ks = cc >> 1, q0 = (cc & 1)*2;
    const int ctg = col >> 4, lcv = col & 15;
    u16* fbase = hfm + (size_t)b*131072 + (size_t)ks*65536 + ((size_t)ctg*64)*8;
    #pragma unroll
    for (int qq=0; qq<2; ++qq){
      int q = q0 + qq;
      u32 p0 = (u32)f2bf(tile[r][ks*32+q*8+0]) | ((u32)f2bf(tile[r][ks*32+q*8+1])<<16);
      u32 p1 = (u32)f2bf(tile[r][ks*32+q*8+2]) | ((u32)f2bf(tile[r][ks*32+q*8+3])<<16);
      u32 p2 = (u32)f2bf(tile[r][ks*32+q*8+4]) | ((u32)f2bf(tile[r][ks*32+q*8+5])<<16);
      u32 p3 = (u32)f2bf(tile[r][ks*32+q*8+6]) | ((u32)f2bf(tile[r][ks*32+q*8+7])<<16);
      *(uint4*)(fbase + (size_t)(q*16 + lcv)*8) = make_uint4(p0,p1,p2,p3);
    }
  }
}

// ---------------------------------------------------------------------------
// K1: row n of A = E E^T. sign-mask (1 pos, 2 neg, 0 zero) + P=softmax(relu) bf16.
// ---------------------------------------------------------------------------
__global__ void k_P(const float* __restrict__ E, u16* __restrict__ P, u8* __restrict__ msk){
  __shared__ float Ew[16];
  __shared__ float arow[2048];
  __shared__ float red[4];
  const int t = threadIdx.x, n = blockIdx.x;
  if (t < 16) Ew[t] = E[n*16 + t];
  __syncthreads();
  float lmax = 0.f;
  for (int i=0;i<8;i++){
    int m = t + 256*i;
    const float* ep = E + m*16;
    float dot = 0.f;
    #pragma unroll
    for (int d=0; d<16; ++d) dot += Ew[d]*ep[d];
    msk[n*2048 + m] = dot > 0.f ? (u8)1 : (dot < 0.f ? (u8)2 : (u8)0);
    float ar = fmaxf(dot, 0.f);
    arow[m] = ar;
    lmax = fmaxf(lmax, ar);
  }
  for (int o=1;o<64;o<<=1) lmax = fmaxf(lmax, __shfl_xor(lmax, o));
  if ((t&63)==0) red[t>>6] = lmax;
  __syncthreads();
  float gmax = fmaxf(fmaxf(red[0],red[1]), fmaxf(red[2],red[3]));
  __syncthreads();
  float lsum = 0.f;
  for (int i=0;i<8;i++){
    int m = t + 256*i;
    float e = expf(arow[m] - gmax);
    arow[m] = e;
    lsum += e;
  }
  for (int o=1;o<64;o<<=1) lsum += __shfl_xor(lsum, o);
  if ((t&63)==0) red[t>>6] = lsum;
  __syncthreads();
  float inv = 1.f/(red[0]+red[1]+red[2]+red[3]);
  for (int i=0;i<8;i++){
    int m = t + 256*i;
    P[n*2048 + m] = f2bf(arow[m]*inv);
  }
}

// ---------------------------------------------------------------------------
// K2x: c1x[b,n,c] = sum_m P[n,m] * x[b,m,c]
// ---------------------------------------------------------------------------
__global__ void k_c1x(const u16* __restrict__ P, const float* __restrict__ x, float* __restrict__ c1x){
  const int t = threadIdx.x;
  const int r = t>>1, c = t&1;
  const int n = blockIdx.x*64 + r, b = blockIdx.y;
  const u16* pr = P + (size_t)n*2048;
  const float* xb = x + (size_t)b*2048*2 + c;
  float acc = 0.f;
  for (int m=0;m<2048;m+=4){
    acc += bf2f(pr[m+0])*xb[(m+0)*2];
    acc += bf2f(pr[m+1])*xb[(m+1)*2];
    acc += bf2f(pr[m+2])*xb[(m+2)*2];
    acc += bf2f(pr[m+3])*xb[(m+3)*2];
  }
  c1x[((size_t)b*2048 + n)*2 + c] = acc;
}

// ---------------------------------------------------------------------------
// K2: Y[b,n,d] = sum_m P[n,m] * Z[b,m,d], Z f32 [B,N,64]. 64x64 tile.
// ---------------------------------------------------------------------------
__global__ void k_conv(const u16* __restrict__ P, const float* __restrict__ Z, float* __restrict__ Y){
  __shared__ float Pt[16][68];
  __shared__ float Zt[16][68];
  const int t = threadIdx.x;
  const int tr = t>>4, tc = t&15;
  const int n0 = blockIdx.x*64, b = blockIdx.y;
  float acc[4][4] = {};
  for (int mt=0; mt<128; ++mt){
    int m0 = mt*16;
    {
      int r = t>>2, c4 = (t&3)*4;
      const u16* pp = P + (size_t)(n0+r)*2048 + m0 + c4;
      u32 p0 = *(const u32*)pp, p1v = *(const u32*)(pp+2);
      Pt[c4+0][r]=bf2f((u16)p0);  Pt[c4+1][r]=bf2f((u16)(p0>>16));
      Pt[c4+2][r]=bf2f((u16)p1v); Pt[c4+3][r]=bf2f((u16)(p1v>>16));
      int mm = t>>4, d0 = (t&15)*4;
      float4 zv = *(const float4*)&Z[((size_t)b*2048 + m0+mm)*64 + d0];
      Zt[mm][d0+0]=zv.x; Zt[mm][d0+1]=zv.y; Zt[mm][d0+2]=zv.z; Zt[mm][d0+3]=zv.w;
    }
    __syncthreads();
    #pragma unroll
    for (int mm=0; mm<16; ++mm){
      float4 a  = *(const float4*)&Pt[mm][tr*4];
      float4 bz = *(const float4*)&Zt[mm][tc*4];
      acc[0][0]+=a.x*bz.x; acc[0][1]+=a.x*bz.y; acc[0][2]+=a.x*bz.z; acc[0][3]+=a.x*bz.w;
      acc[1][0]+=a.y*bz.x; acc[1][1]+=a.y*bz.y; acc[1][2]+=a.y*bz.z; acc[1][3]+=a.y*bz.w;
      acc[2][0]+=a.z*bz.x; acc[2][1]+=a.z*bz.y; acc[2][2]+=a.z*bz.z; acc[2][3]+=a.z*bz.w;
      acc[3][0]+=a.w*bz.x; acc[3][1]+=a.w*bz.y; acc[3][2]+=a.w*bz.z; acc[3][3]+=a.w*bz.w;
    }
    __syncthreads();
  }
  #pragma unroll
  for (int i=0;i<4;i++){
    float4 v = make_float4(acc[i][0],acc[i][1],acc[i][2],acc[i][3]);
    *(float4*)&Y[((size_t)b*2048 + n0 + tr*4 + i)*64 + tc*4] = v;
  }
}

// ---------------------------------------------------------------------------
// K3: gate SAGC -> zs = z*state, rws = r. One block per node n.
// ---------------------------------------------------------------------------
__global__ void k_gate(const float* __restrict__ E, const float* __restrict__ gw, const float* __restrict__ gb,
                       const float* __restrict__ x, const float* __restrict__ state,
                       const float* __restrict__ c1x, const float* __restrict__ c1s,
                       float* __restrict__ zs, float* __restrict__ rws){
  __shared__ float Ew[16];
  __shared__ float bnv[128];
  __shared__ float Wn[2][66][64];
  __shared__ float xg4[4][2][66];
  const int t = threadIdx.x, n = blockIdx.x;
  if (t < 16) Ew[t] = E[n*16 + t];
  __syncthreads();
  if (t < 128){
    float a = 0.f;
    #pragma unroll
    for (int e=0;e<16;e++) a += Ew[e]*gb[e*128 + t];
    bnv[t] = a;
  }
  for (int half=0; half<2; ++half){
    for (int idx=t; idx<8448; idx+=256){
      int o = idx & 63, rest = idx>>6, i = rest % 66, k = rest / 66;
      float a = 0.f;
      #pragma unroll
      for (int e=0;e<16;e++) a += Ew[e]*gw[((e*2+k)*66 + i)*128 + half*64 + o];
      Wn[k][i][o] = a;
    }
    __syncthreads();
    for (int bb=0; bb<4; ++bb){
      for (int idx=t; idx<528; idx+=256){
        int bi = idx/132, rem = idx%132, k = rem/66, i = rem%66;
        int b = bb*4 + bi;
        float v;
        if (k==0) v = (i<2) ? x[((size_t)b*2048+n)*2 + i] : state[((size_t)b*2048+n)*64 + (i-2)];
        else      v = (i<2) ? c1x[((size_t)b*2048+n)*2 + i] : c1s[((size_t)b*2048+n)*64 + (i-2)];
        xg4[bi][k][i] = v;
      }
      __syncthreads();
      {
        int bi = t>>6, o = t&63, b = bb*4 + bi;
        float a = 0.f;
        #pragma unroll
        for (int k=0;k<2;k++)
          for (int i=0;i<66;i++) a += xg4[bi][k][i]*Wn[k][i][o];
        a += bnv[half*64 + o];
        float s = 1.f/(1.f + expf(-a));
        if (half==0) zs[((size_t)b*2048+n)*64 + o] = s*state[((size_t)b*2048+n)*64 + o];
        else         rws[((size_t)b*2048+n)*64 + o] = s;
      }
      __syncthreads();
    }
  }
}

// ---------------------------------------------------------------------------
// K3b: update SAGC -> hc -> h = r*state + (1-r)*hc.
// ---------------------------------------------------------------------------
__global__ void k_upd(const float* __restrict__ E, const float* __restrict__ uw, const float* __restrict__ ub,
                      const float* __restrict__ x, const float* __restrict__ state,
                      const float* __restrict__ zs, const float* __restrict__ c1x, const float* __restrict__ c2s,
                      const float* __restrict__ rws, float* __restrict__ h){
  __shared__ float Ew[16];
  __shared__ float bnu[64];
  __shared__ float Wn[2][66][64];
  __shared__ float xg4[4][2][66];
  const int t = threadIdx.x, n = blockIdx.x;
  if (t < 16) Ew[t] = E[n*16 + t];
  __syncthreads();
  if (t < 64){
    float a = 0.f;
    #pragma unroll
    for (int e=0;e<16;e++) a += Ew[e]*ub[e*64 + t];
    bnu[t] = a;
  }
  for (int idx=t; idx<8448; idx+=256){
    int o = idx & 63, rest = idx>>6, i = rest % 66, k = rest / 66;
    float a = 0.f;
    #pragma unroll
    for (int e=0;e<16;e++) a += Ew[e]*uw[((e*2+k)*66 + i)*64 + o];
    Wn[k][i][o] = a;
  }
  __syncthreads();
  for (int bb=0; bb<4; ++bb){
    for (int idx=t; idx<528; idx+=256){
      int bi = idx/132, rem = idx%132, k = rem/66, i = rem%66;
      int b = bb*4 + bi;
      float v;
      if (k==0) v = (i<2) ? x[((size_t)b*2048+n)*2 + i] : zs[((size_t)b*2048+n)*64 + (i-2)];
      else      v = (i<2) ? c1x[((size_t)b*2048+n)*2 + i] : c2s[((size_t)b*2048+n)*64 + (i-2)];
      xg4[bi][k][i] = v;
    }
    __syncthreads();
    {
      int bi = t>>6, o = t&63, b = bb*4 + bi;
      float a = 0.f;
      #pragma unroll
      for (int k=0;k<2;k++)
        for (int i=0;i<66;i++) a += xg4[bi][k][i]*Wn[k][i][o];
      float hc = tanhf(a + bnu[o]);
      float rv = rws[((size_t)b*2048+n)*64 + o];
      h[((size_t)b*2048+n)*64 + o] = rv*state[((size_t)b*2048+n)*64 + o] + (1.f - rv)*hc;
    }
    __syncthreads();
  }
}

// ---------------------------------------------------------------------------
// K5: fused degrees, fp8 MFMA, coalesced fragment-major operands.
// 1D grid 2048 blocks, 512 threads. XCD-mask swizzle: mask = (id>>2)&1.
// LDS: S fp8 [32][2056] dynamic (65,792 B) + 2 KB static.
// Scaling: S stores S/8; W stores 16W -> logits = 0.5*acc; deg stored *256.
// ---------------------------------------------------------------------------
#define SROW8 2056

__global__ void __launch_bounds__(512,2) k_deg(
    const u8* __restrict__ msk, const u16* __restrict__ hb16,
    const u8* __restrict__ Wc8, const u8* __restrict__ Wd8,
    const u8* __restrict__ ht8p, const u16* __restrict__ hfm,
    float* __restrict__ outc, float* __restrict__ outd){
  extern __shared__ u8 S[];
  __shared__ float redm[32][8];
  __shared__ float redsum[32][8];
  const int t = threadIdx.x;
  const int w = t >> 6, lane = t & 63, lc = lane & 15, q = lane >> 4;
  // XCD-mask swizzle: with round-robin XCD dispatch, XCDs 0-3 get mask 0,
  // XCDs 4-7 get mask 1 -> each XCD's 4MB L2 holds exactly its own W copy.
  const int id = blockIdx.x;
  const int mask = (id >> 2) & 1;
  const int sub = ((id & 3) << 8) | (id >> 3);
  const int b = sub & 15, n0 = (sub >> 4) * 32;
  const u8* W8 = mask ? Wd8 : Wc8;
  const u8 want = mask ? (u8)2 : (u8)1;
  const u16* hbb = hb16 + (size_t)b*2048*64;
  const u16* hfb = hfm + (size_t)b*131072;
  const u8* htb = ht8p + (size_t)b*131072;

  // ---- phase 1: S[r][m] = fp8( (mask ? h_n.h_m : 0) / 8 ) ----
  {
    bf16x8 A[2][2];
    #pragma unroll
    for (int rt=0; rt<2; ++rt)
      #pragma unroll
      for (int ks=0; ks<2; ++ks)
        A[rt][ks] = *(const bf16x8*)&hbb[(size_t)(n0 + rt*16 + lc)*64 + ks*32 + q*8];
    for (int ct=0; ct<16; ++ct){
      const int ctg = w*16 + ct;
      const int mcol = ctg*16 + lc;
      bf16x8 B0 = *(const bf16x8*)(hfm + (size_t)b*131072 + (size_t)ctg*512 + lane*8);
      bf16x8 B1 = *(const bf16x8*)(hfm + (size_t)b*131072 + 65536 + (size_t)ctg*512 + lane*8);
      f32x4 a0 = {0.f,0.f,0.f,0.f}, a1 = {0.f,0.f,0.f,0.f};
      a0 = mfma_bf16(A[0][0], B0, a0); a0 = mfma_bf16(A[0][1], B1, a0);
      a1 = mfma_bf16(A[1][0], B0, a1); a1 = mfma_bf16(A[1][1], B1, a1);
      #pragma unroll
      for (int i=0;i<4;i++){
        int r0 = q*4 + i, r1 = 16 + q*4 + i;
        float v0 = (msk[(size_t)(n0+r0)*2048 + mcol]==want) ? a0[i]*0.125f : 0.f;
        float v1 = (msk[(size_t)(n0+r1)*2048 + mcol]==want) ? a1[i]*0.125f : 0.f;
        S[r0*SROW8 + mcol] = f2fp8(v0);
        S[r1*SROW8 + mcol] = f2fp8(v1);
      }
    }
  }
  __syncthreads();

  // ---- phase 2: logits = S @ W ; wave owns k-cols [w*256, w*256+256) ----
  f32x4 acc0[16], acc1[16];
  #pragma unroll
  for (int ct=0;ct<16;ct++){ acc0[ct] = (f32x4){0.f,0.f,0.f,0.f}; acc1[ct] = (f32x4){0.f,0.f,0.f,0.f}; }
  {
    const u8* sp0 = S + lc*SROW8 + q*8;
    const u8* sp1 = sp0 + 16*SROW8;
    #pragma unroll 1
    for (int pt=0; pt<32; ++pt){
      long a0e = *(const long*)(sp0 + pt*64);
      long a0o = *(const long*)(sp0 + pt*64 + 32);
      long a1e = *(const long*)(sp1 + pt*64);
      long a1o = *(const long*)(sp1 + pt*64 + 32);
      const u8* wpt = W8 + ((size_t)pt*128 + w*16)*1024 + lane*16;
      uint4 bv[16];
      #pragma unroll
      for (int ct=0; ct<16; ++ct)
        bv[ct] = *(const uint4*)(wpt + ct*1024);
      #pragma unroll
      for (int ct=0; ct<16; ++ct){
        long be = lo64(bv[ct]), bo = hi64(bv[ct]);
        acc0[ct] = mfma_fp8(a0e, be, acc0[ct]);
        acc1[ct] = mfma_fp8(a1e, be, acc1[ct]);
        acc0[ct] = mfma_fp8(a0o, bo, acc0[ct]);
        acc1[ct] = mfma_fp8(a1o, bo, acc1[ct]);
      }
    }
  }

  // ---- phase 3: row softmax over k (true logits = 0.5*acc) ----
  float gmax0[4], gmax1[4], gsc0[4], gsc1[4];
  #pragma unroll
  for (int i=0;i<4;i++){
    float mx0 = acc0[0][i], mx1 = acc1[0][i];
    #pragma unroll
    for (int ct=1; ct<16; ++ct){ mx0 = fmaxf(mx0, acc0[ct][i]); mx1 = fmaxf(mx1, acc1[ct][i]); }
    mx0 = fmaxf(mx0, __shfl_xor(mx0, 1)); mx1 = fmaxf(mx1, __shfl_xor(mx1, 1));
    mx0 = fmaxf(mx0, __shfl_xor(mx0, 2)); mx1 = fmaxf(mx1, __shfl_xor(mx1, 2));
    mx0 = fmaxf(mx0, __shfl_xor(mx0, 4)); mx1 = fmaxf(mx1, __shfl_xor(mx1, 4));
    mx0 = fmaxf(mx0, __shfl_xor(mx0, 8)); mx1 = fmaxf(mx1, __shfl_xor(mx1, 8));
    if (lc == 0){ redm[q*4+i][w] = mx0; redm[16+q*4+i][w] = mx1; }
  }
  __syncthreads();
  #pragma unroll
  for (int i=0;i<4;i++){
    float m0 = redm[q*4+i][0], m1 = redm[16+q*4+i][0];
    #pragma unroll
    for (int j=1;j<8;j++){ m0 = fmaxf(m0, redm[q*4+i][j]); m1 = fmaxf(m1, redm[16+q*4+i][j]); }
    gmax0[i] = m0; gmax1[i] = m1;
  }
  #pragma unroll
  for (int i=0;i<4;i++){
    float s0 = 0.f, s1 = 0.f;
    #pragma unroll
    for (int ct=0; ct<16; ++ct){
      float e0 = __expf(0.5f*(acc0[ct][i] - gmax0[i]));
      float e1 = __expf(0.5f*(acc1[ct][i] - gmax1[i]));
      acc0[ct][i] = e0; acc1[ct][i] = e1;
      s0 += e0; s1 += e1;
    }
    s0 += __shfl_xor(s0, 1); s1 += __shfl_xor(s1, 1);
    s0 += __shfl_xor(s0, 2); s1 += __shfl_xor(s1, 2);
    s0 += __shfl_xor(s0, 4); s1 += __shfl_xor(s1, 4);
    s0 += __shfl_xor(s0, 8); s1 += __shfl_xor(s1, 8);
    if (lc == 0){ redsum[q*4+i][w] = s0; redsum[16+q*4+i][w] = s1; }
  }
  __syncthreads();
  #pragma unroll
  for (int i=0;i<4;i++){
    float s0 = 0.f, s1 = 0.f;
    #pragma unroll
    for (int j=0;j<8;j++){ s0 += redsum[q*4+i][j]; s1 += redsum[16+q*4+i][j]; }
    gsc0[i] = 256.f/s0; gsc1[i] = 256.f/s1;
  }
  // writeback deg*256 as fp8 (phase-2 S reads all completed before the barriers above)
  #pragma unroll
  for (int ct=0; ct<16; ++ct){
    const int col = w*256 + ct*16 + lc;
    #pragma unroll
    for (int i=0;i<4;i++){
      S[(q*4+i)*SROW8 + col]      = f2fp8(acc0[ct][i]*gsc0[i]);
      S[(16+q*4+i)*SROW8 + col]   = f2fp8(acc1[ct][i]*gsc1[i]);
    }
  }
  __syncthreads();

  // ---- phase 4: out = (deg*256) @ h / 256 ; wave (rt4=w>>2, dt=w&3) ----
  {
    const int rt4 = w >> 2, dt = w & 3;
    f32x4 o = {0.f,0.f,0.f,0.f};
    const u8* abase = S + (size_t)(rt4*16 + lc)*SROW8 + q*8;
    const u8* bbase = htb + (size_t)dt*1024 + lane*16;
    #pragma unroll 1
    for (int pt=0; pt<32; ++pt){
      long ae = *(const long*)(abase + pt*64);
      long ao = *(const long*)(abase + pt*64 + 32);
      uint4 bv = *(const uint4*)(bbase + (size_t)pt*4096);
      o = mfma_fp8(ae, lo64(bv), o);
      o = mfma_fp8(ao, hi64(bv), o);
    }
    float* op = (mask ? outd : outc) + (size_t)b*2048*64;
    #pragma unroll
    for (int i=0;i<4;i++)
      op[(size_t)(n0 + rt4*16 + q*4 + i)*64 + dt*16 + lc] = o[i]*(1.f/256.f);
  }
}

// ---------------------------------------------------------------------------
// K6: numerator = 0.8h - 0.1 outc + 0.1 outd  -> f32 output
// ---------------------------------------------------------------------------
__global__ void k_final(const float* __restrict__ h, const float* __restrict__ outc,
                        const float* __restrict__ outd, float* __restrict__ out){
  size_t i = (size_t)blockIdx.x*256 + threadIdx.x;
  out[i] = 0.8f*h[i] - 0.1f*outc[i] + 0.1f*outd[i];
}

// ---------------------------------------------------------------------------
extern "C" void kernel_launch(void* const* d_in, const int* in_sizes, int n_in,
                              void* d_out, int out_size, void* d_ws, size_t ws_size,
                              hipStream_t stream) {
  const float* x     = (const float*)d_in[0];
  const float* state = (const float*)d_in[1];
  const float* E     = (const float*)d_in[2];
  const float* Wc    = (const float*)d_in[3];
  const float* Wd    = (const float*)d_in[4];
  const float* gw    = (const float*)d_in[5];
  const float* gb    = (const float*)d_in[6];
  const float* uw    = (const float*)d_in[7];
  const float* ub    = (const float*)d_in[8];

  // workspace layout (bytes). Total 73,662,464 B = 70.2 MB.
  char* base = (char*)d_ws;
  u16*   P    = (u16*)(base + 0);           //  8,388,608
  u8*    msk  = (u8*) (base + 8388608);     //  4,194,304
  u8*    Wc8  = (u8*) (base + 12582912);    //  4,194,304
  u8*    Wd8  = (u8*) (base + 16777216);    //  4,194,304
  u16*   hb16 = (u16*)(base + 20971520);    //  4,194,304
  u8*    ht8p = (u8*) (base + 25165824);    //  2,097,152
  u16*   hfm  = (u16*)(base + 27262976);    //  4,194,304
  float* c1x  = (float*)(base + 31457280);  //    262,144
  float* c1s  = (float*)(base + 31719424);  //  8,388,608
  float* zs   = (float*)(base + 40108032);  //  8,388,608
  float* rws  = (float*)(base + 48496640);  //  8,388,608
  float* c2s  = (float*)(base + 56885248);  //  8,388,608
  float* h    = (float*)(base + 65273856);  //  8,388,608
  float* oc   = c1s;                        // dead after k_gate
  float* od   = c2s;                        // dead after k_upd

  k_w8<<<dim3(32,32,2), 256, 0, stream>>>(Wc, Wd, Wc8, Wd8);
  k_P<<<2048, 256, 0, stream>>>(E, P, msk);
  k_c1x<<<dim3(32,16), 128, 0, stream>>>(P, x, c1x);
  k_conv<<<dim3(32,16), 256, 0, stream>>>(P, state, c1s);
  k_gate<<<2048, 256, 0, stream>>>(E, gw, gb, x, state, c1x, c1s, zs, rws);
  k_conv<<<dim3(32,16), 256, 0, stream>>>(P, zs, c2s);
  k_upd<<<2048, 256, 0, stream>>>(E, uw, ub, x, state, zs, c1x, c2s, rws, h);
  k_hcvt<<<dim3(32,16), 256, 0, stream>>>(h, hb16, ht8p, hfm);

  const int deg_lds = 32*SROW8;   // 65,792 B dynamic
  hipFuncSetAttribute((const void*)k_deg, hipFuncAttributeMaxDynamicSharedMemorySize, deg_lds);
  k_deg<<<2048, 512, deg_lds, stream>>>(msk, hb16, Wc8, Wd8, ht8p, hfm, oc, od);

  k_final<<<8192, 256, 0, stream>>>(h, oc, od, (float*)d_out);
}

// Round 7
// 2312.889 us; speedup vs baseline: 3.5513x; 1.0034x over previous
//
#include <hip/hip_runtime.h>
#include <hip/hip_bf16.h>

typedef unsigned short u16;
typedef unsigned int   u32;
typedef unsigned char  u8;

typedef __attribute__((ext_vector_type(8))) short bf16x8;
typedef __attribute__((ext_vector_type(4))) float f32x4;

static __device__ __forceinline__ float bf2f(u16 u){ return __uint_as_float(((u32)u)<<16); }
static __device__ __forceinline__ u16 f2bf(float f){
  u32 u = __float_as_uint(f);
  u32 r = (u + 0x7fff + ((u>>16)&1)) >> 16;   // RNE; inputs finite
  return (u16)r;
}

// fp8 e4m3 (OCP) helpers — HW cvt, saturating via pre-clamp
static __device__ __forceinline__ u8 f2fp8(float v){
  v = fminf(440.f, fmaxf(-440.f, v));
  return (u8)(__builtin_amdgcn_cvt_pk_fp8_f32(v, 0.f, 0, false) & 0xff);
}
static __device__ __forceinline__ u32 pk4_fp8(float a, float b, float c, float d){
  int w = __builtin_amdgcn_cvt_pk_fp8_f32(a, b, 0, false);
  w = __builtin_amdgcn_cvt_pk_fp8_f32(c, d, w, true);
  return (u32)w;
}

static __device__ __forceinline__ f32x4 mfma_bf16(bf16x8 a, bf16x8 b, f32x4 c){
  return __builtin_amdgcn_mfma_f32_16x16x32_bf16(a, b, c, 0, 0, 0);
}
static __device__ __forceinline__ f32x4 mfma_fp8(long a, long b, f32x4 c){
  return __builtin_amdgcn_mfma_f32_16x16x32_fp8_fp8(a, b, c, 0, 0, 0);
}
static __device__ __forceinline__ long lo64(uint4 v){ return (long)(((unsigned long long)v.y<<32) | v.x); }
static __device__ __forceinline__ long hi64(uint4 v){ return (long)(((unsigned long long)v.w<<32) | v.z); }

// ---------------------------------------------------------------------------
// K-w8: W f32 [m][k] -> fragment-major fp8 (16*W), 1KB-contiguous per (pt,ctg).
// grid (32,32,2), block 256.
// ---------------------------------------------------------------------------
__global__ void k_w8(const float* __restrict__ Wc, const float* __restrict__ Wd,
                     u8* __restrict__ Wc8, u8* __restrict__ Wd8){
  __shared__ float tile[64][65];
  const float* src = blockIdx.z ? Wd : Wc;
  u8* dst = blockIdx.z ? Wd8 : Wc8;
  const int m0 = blockIdx.x*64, k0 = blockIdx.y*64;
  const int t = threadIdx.x, r = t & 63, cc = t >> 6;
  #pragma unroll
  for (int j=0;j<4;j++){
    float4 v = *(const float4*)&src[(size_t)(m0+r)*2048 + k0 + cc*16 + j*4];
    tile[r][cc*16+j*4+0]=v.x; tile[r][cc*16+j*4+1]=v.y;
    tile[r][cc*16+j*4+2]=v.z; tile[r][cc*16+j*4+3]=v.w;
  }
  __syncthreads();
  u32 f0 = pk4_fp8(16.f*tile[cc*16+ 0][r], 16.f*tile[cc*16+ 1][r], 16.f*tile[cc*16+ 2][r], 16.f*tile[cc*16+ 3][r]);
  u32 f1 = pk4_fp8(16.f*tile[cc*16+ 4][r], 16.f*tile[cc*16+ 5][r], 16.f*tile[cc*16+ 6][r], 16.f*tile[cc*16+ 7][r]);
  u32 f2 = pk4_fp8(16.f*tile[cc*16+ 8][r], 16.f*tile[cc*16+ 9][r], 16.f*tile[cc*16+10][r], 16.f*tile[cc*16+11][r]);
  u32 f3 = pk4_fp8(16.f*tile[cc*16+12][r], 16.f*tile[cc*16+13][r], 16.f*tile[cc*16+14][r], 16.f*tile[cc*16+15][r]);
  const int k = k0 + r, mbase = m0 + cc*16;
  const int pt = mbase >> 6, half = (mbase >> 5) & 1, q0 = (mbase >> 3) & 3;
  const int ctg = k >> 4, lcv = k & 15;
  u8* dbase = dst + (size_t)((pt*128 + ctg)*64)*16 + half*8;
  *(uint2*)(dbase + (q0*16 + lcv)*16)     = make_uint2(f0, f1);
  *(uint2*)(dbase + ((q0+1)*16 + lcv)*16) = make_uint2(f2, f3);
}

// ---------------------------------------------------------------------------
// K-hcvt: h f32 [b][m][64] -> hb16 (bf16 row-major), hfm (bf16 frag-major B for
// phase 1), ht8p (fp8 frag-major B for phase 4). grid (32,16), block 256.
// ---------------------------------------------------------------------------
__global__ void k_hcvt(const float* __restrict__ h, u16* __restrict__ hb16,
                       u8* __restrict__ ht8p, u16* __restrict__ hfm){
  __shared__ float tile[64][65];
  const int k0 = blockIdx.x*64, b = blockIdx.y;
  const int t = threadIdx.x, r = t & 63, cc = t >> 6;
  const float* src = h + ((size_t)b*2048 + k0)*64;
  u32 hw[8];
  #pragma unroll
  for (int j=0;j<4;j++){
    float4 v = *(const float4*)&src[(size_t)r*64 + cc*16 + j*4];
    tile[r][cc*16+j*4+0]=v.x; tile[r][cc*16+j*4+1]=v.y;
    tile[r][cc*16+j*4+2]=v.z; tile[r][cc*16+j*4+3]=v.w;
    hw[2*j]   = (u32)f2bf(v.x) | ((u32)f2bf(v.y)<<16);
    hw[2*j+1] = (u32)f2bf(v.z) | ((u32)f2bf(v.w)<<16);
  }
  u16* hp = hb16 + (((size_t)b*2048 + k0 + r)*64 + cc*16);
  *(uint4*)hp     = make_uint4(hw[0],hw[1],hw[2],hw[3]);
  *(uint4*)(hp+8) = make_uint4(hw[4],hw[5],hw[6],hw[7]);
  __syncthreads();
  {
    u32 f0 = pk4_fp8(tile[cc*16+ 0][r], tile[cc*16+ 1][r], tile[cc*16+ 2][r], tile[cc*16+ 3][r]);
    u32 f1 = pk4_fp8(tile[cc*16+ 4][r], tile[cc*16+ 5][r], tile[cc*16+ 6][r], tile[cc*16+ 7][r]);
    u32 f2 = pk4_fp8(tile[cc*16+ 8][r], tile[cc*16+ 9][r], tile[cc*16+10][r], tile[cc*16+11][r]);
    u32 f3 = pk4_fp8(tile[cc*16+12][r], tile[cc*16+13][r], tile[cc*16+14][r], tile[cc*16+15][r]);
    const int pt = k0 >> 6, half = cc >> 1, q0 = (cc & 1)*2;
    const int ctg = r >> 4, lcv = r & 15;
    u8* dbase = ht8p + (size_t)b*131072 + (size_t)((pt*4 + ctg)*64)*16 + half*8;
    *(uint2*)(dbase + (q0*16 + lcv)*16)     = make_uint2(f0, f1);
    *(uint2*)(dbase + ((q0+1)*16 + lcv)*16) = make_uint2(f2, f3);
  }
  {
    const int col = k0 + r, ks = cc >> 1, q0 = (cc & 1)*2;
    const int ctg = col >> 4, lcv = col & 15;
    u16* fbase = hfm + (size_t)b*131072 + (size_t)ks*65536 + ((size_t)ctg*64)*8;
    #pragma unroll
    for (int qq=0; qq<2; ++qq){
      int q = q0 + qq;
      u32 p0 = (u32)f2bf(tile[r][ks*32+q*8+0]) | ((u32)f2bf(tile[r][ks*32+q*8+1])<<16);
      u32 p1 = (u32)f2bf(tile[r][ks*32+q*8+2]) | ((u32)f2bf(tile[r][ks*32+q*8+3])<<16);
      u32 p2 = (u32)f2bf(tile[r][ks*32+q*8+4]) | ((u32)f2bf(tile[r][ks*32+q*8+5])<<16);
      u32 p3 = (u32)f2bf(tile[r][ks*32+q*8+6]) | ((u32)f2bf(tile[r][ks*32+q*8+7])<<16);
      *(uint4*)(fbase + (size_t)(q*16 + lcv)*8) = make_uint4(p0,p1,p2,p3);
    }
  }
}

// ---------------------------------------------------------------------------
// K1: row n of A = E E^T. sign-mask (1 pos, 2 neg) + P=softmax(relu) bf16.
// ---------------------------------------------------------------------------
__global__ void k_P(const float* __restrict__ E, u16* __restrict__ P, u8* __restrict__ msk){
  __shared__ float Ew[16];
  __shared__ float arow[2048];
  __shared__ float red[4];
  const int t = threadIdx.x, n = blockIdx.x;
  if (t < 16) Ew[t] = E[n*16 + t];
  __syncthreads();
  float lmax = 0.f;
  for (int i=0;i<8;i++){
    int m = t + 256*i;
    const float* ep = E + m*16;
    float dot = 0.f;
    #pragma unroll
    for (int d=0; d<16; ++d) dot += Ew[d]*ep[d];
    msk[n*2048 + m] = dot > 0.f ? (u8)1 : (dot < 0.f ? (u8)2 : (u8)0);
    float ar = fmaxf(dot, 0.f);
    arow[m] = ar;
    lmax = fmaxf(lmax, ar);
  }
  for (int o=1;o<64;o<<=1) lmax = fmaxf(lmax, __shfl_xor(lmax, o));
  if ((t&63)==0) red[t>>6] = lmax;
  __syncthreads();
  float gmax = fmaxf(fmaxf(red[0],red[1]), fmaxf(red[2],red[3]));
  __syncthreads();
  float lsum = 0.f;
  for (int i=0;i<8;i++){
    int m = t + 256*i;
    float e = expf(arow[m] - gmax);
    arow[m] = e;
    lsum += e;
  }
  for (int o=1;o<64;o<<=1) lsum += __shfl_xor(lsum, o);
  if ((t&63)==0) red[t>>6] = lsum;
  __syncthreads();
  float inv = 1.f/(red[0]+red[1]+red[2]+red[3]);
  for (int i=0;i<8;i++){
    int m = t + 256*i;
    P[n*2048 + m] = f2bf(arow[m]*inv);
  }
}

// ---------------------------------------------------------------------------
// K-mbits: msk u8 [n][m] -> transposed bitmaps mp2/mn2 u32 [n/32][m]:
// bit (n&31) of mp2[n>>5][m] = (msk[n][m]==1). grid (2048, 8), block 256.
// ---------------------------------------------------------------------------
__global__ void k_mbits(const u8* __restrict__ msk, u32* __restrict__ mp2, u32* __restrict__ mn2){
  const int m = blockIdx.x, nb = blockIdx.y*256;
  const int t = threadIdx.x, w = t>>6, lane = t&63;
  u8 v = msk[(size_t)(nb + t)*2048 + m];
  unsigned long long bp = __ballot(v == (u8)1);
  unsigned long long bn = __ballot(v == (u8)2);
  if (lane == 0){
    int wi = (nb + w*64) >> 5;
    mp2[(size_t)wi*2048 + m]     = (u32)bp;
    mp2[(size_t)(wi+1)*2048 + m] = (u32)(bp>>32);
    mn2[(size_t)wi*2048 + m]     = (u32)bn;
    mn2[(size_t)(wi+1)*2048 + m] = (u32)(bn>>32);
  }
}

// ---------------------------------------------------------------------------
// K2x: c1x[b,n,c] = sum_m P[n,m] * x[b,m,c]
// ---------------------------------------------------------------------------
__global__ void k_c1x(const u16* __restrict__ P, const float* __restrict__ x, float* __restrict__ c1x){
  const int t = threadIdx.x;
  const int r = t>>1, c = t&1;
  const int n = blockIdx.x*64 + r, b = blockIdx.y;
  const u16* pr = P + (size_t)n*2048;
  const float* xb = x + (size_t)b*2048*2 + c;
  float acc = 0.f;
  for (int m=0;m<2048;m+=4){
    acc += bf2f(pr[m+0])*xb[(m+0)*2];
    acc += bf2f(pr[m+1])*xb[(m+1)*2];
    acc += bf2f(pr[m+2])*xb[(m+2)*2];
    acc += bf2f(pr[m+3])*xb[(m+3)*2];
  }
  c1x[((size_t)b*2048 + n)*2 + c] = acc;
}

// ---------------------------------------------------------------------------
// K2: Y[b,n,d] = sum_m P[n,m] * Z[b,m,d], Z f32 [B,N,64]. 64x64 tile.
// ---------------------------------------------------------------------------
__global__ void k_conv(const u16* __restrict__ P, const float* __restrict__ Z, float* __restrict__ Y){
  __shared__ float Pt[16][68];
  __shared__ float Zt[16][68];
  const int t = threadIdx.x;
  const int tr = t>>4, tc = t&15;
  const int n0 = blockIdx.x*64, b = blockIdx.y;
  float acc[4][4] = {};
  for (int mt=0; mt<128; ++mt){
    int m0 = mt*16;
    {
      int r = t>>2, c4 = (t&3)*4;
      const u16* pp = P + (size_t)(n0+r)*2048 + m0 + c4;
      u32 p0 = *(const u32*)pp, p1v = *(const u32*)(pp+2);
      Pt[c4+0][r]=bf2f((u16)p0);  Pt[c4+1][r]=bf2f((u16)(p0>>16));
      Pt[c4+2][r]=bf2f((u16)p1v); Pt[c4+3][r]=bf2f((u16)(p1v>>16));
      int mm = t>>4, d0 = (t&15)*4;
      float4 zv = *(const float4*)&Z[((size_t)b*2048 + m0+mm)*64 + d0];
      Zt[mm][d0+0]=zv.x; Zt[mm][d0+1]=zv.y; Zt[mm][d0+2]=zv.z; Zt[mm][d0+3]=zv.w;
    }
    __syncthreads();
    #pragma unroll
    for (int mm=0; mm<16; ++mm){
      float4 a  = *(const float4*)&Pt[mm][tr*4];
      float4 bz = *(const float4*)&Zt[mm][tc*4];
      acc[0][0]+=a.x*bz.x; acc[0][1]+=a.x*bz.y; acc[0][2]+=a.x*bz.z; acc[0][3]+=a.x*bz.w;
      acc[1][0]+=a.y*bz.x; acc[1][1]+=a.y*bz.y; acc[1][2]+=a.y*bz.z; acc[1][3]+=a.y*bz.w;
      acc[2][0]+=a.z*bz.x; acc[2][1]+=a.z*bz.y; acc[2][2]+=a.z*bz.z; acc[2][3]+=a.z*bz.w;
      acc[3][0]+=a.w*bz.x; acc[3][1]+=a.w*bz.y; acc[3][2]+=a.w*bz.z; acc[3][3]+=a.w*bz.w;
    }
    __syncthreads();
  }
  #pragma unroll
  for (int i=0;i<4;i++){
    float4 v = make_float4(acc[i][0],acc[i][1],acc[i][2],acc[i][3]);
    *(float4*)&Y[((size_t)b*2048 + n0 + tr*4 + i)*64 + tc*4] = v;
  }
}

// ---------------------------------------------------------------------------
// K3: gate SAGC -> zs = z*state, rws = r. One block per node n.
// ---------------------------------------------------------------------------
__global__ void k_gate(const float* __restrict__ E, const float* __restrict__ gw, const float* __restrict__ gb,
                       const float* __restrict__ x, const float* __restrict__ state,
                       const float* __restrict__ c1x, const float* __restrict__ c1s,
                       float* __restrict__ zs, float* __restrict__ rws){
  __shared__ float Ew[16];
  __shared__ float bnv[128];
  __shared__ float Wn[2][66][64];
  __shared__ float xg4[4][2][66];
  const int t = threadIdx.x, n = blockIdx.x;
  if (t < 16) Ew[t] = E[n*16 + t];
  __syncthreads();
  if (t < 128){
    float a = 0.f;
    #pragma unroll
    for (int e=0;e<16;e++) a += Ew[e]*gb[e*128 + t];
    bnv[t] = a;
  }
  for (int half=0; half<2; ++half){
    for (int idx=t; idx<8448; idx+=256){
      int o = idx & 63, rest = idx>>6, i = rest % 66, k = rest / 66;
      float a = 0.f;
      #pragma unroll
      for (int e=0;e<16;e++) a += Ew[e]*gw[((e*2+k)*66 + i)*128 + half*64 + o];
      Wn[k][i][o] = a;
    }
    __syncthreads();
    for (int bb=0; bb<4; ++bb){
      for (int idx=t; idx<528; idx+=256){
        int bi = idx/132, rem = idx%132, k = rem/66, i = rem%66;
        int b = bb*4 + bi;
        float v;
        if (k==0) v = (i<2) ? x[((size_t)b*2048+n)*2 + i] : state[((size_t)b*2048+n)*64 + (i-2)];
        else      v = (i<2) ? c1x[((size_t)b*2048+n)*2 + i] : c1s[((size_t)b*2048+n)*64 + (i-2)];
        xg4[bi][k][i] = v;
      }
      __syncthreads();
      {
        int bi = t>>6, o = t&63, b = bb*4 + bi;
        float a = 0.f;
        #pragma unroll
        for (int k=0;k<2;k++)
          for (int i=0;i<66;i++) a += xg4[bi][k][i]*Wn[k][i][o];
        a += bnv[half*64 + o];
        float s = 1.f/(1.f + expf(-a));
        if (half==0) zs[((size_t)b*2048+n)*64 + o] = s*state[((size_t)b*2048+n)*64 + o];
        else         rws[((size_t)b*2048+n)*64 + o] = s;
      }
      __syncthreads();
    }
  }
}

// ---------------------------------------------------------------------------
// K3b: update SAGC -> hc -> h = r*state + (1-r)*hc.
// ---------------------------------------------------------------------------
__global__ void k_upd(const float* __restrict__ E, const float* __restrict__ uw, const float* __restrict__ ub,
                      const float* __restrict__ x, const float* __restrict__ state,
                      const float* __restrict__ zs, const float* __restrict__ c1x, const float* __restrict__ c2s,
                      const float* __restrict__ rws, float* __restrict__ h){
  __shared__ float Ew[16];
  __shared__ float bnu[64];
  __shared__ float Wn[2][66][64];
  __shared__ float xg4[4][2][66];
  const int t = threadIdx.x, n = blockIdx.x;
  if (t < 16) Ew[t] = E[n*16 + t];
  __syncthreads();
  if (t < 64){
    float a = 0.f;
    #pragma unroll
    for (int e=0;e<16;e++) a += Ew[e]*ub[e*64 + t];
    bnu[t] = a;
  }
  for (int idx=t; idx<8448; idx+=256){
    int o = idx & 63, rest = idx>>6, i = rest % 66, k = rest / 66;
    float a = 0.f;
    #pragma unroll
    for (int e=0;e<16;e++) a += Ew[e]*uw[((e*2+k)*66 + i)*64 + o];
    Wn[k][i][o] = a;
  }
  __syncthreads();
  for (int bb=0; bb<4; ++bb){
    for (int idx=t; idx<528; idx+=256){
      int bi = idx/132, rem = idx%132, k = rem/66, i = rem%66;
      int b = bb*4 + bi;
      float v;
      if (k==0) v = (i<2) ? x[((size_t)b*2048+n)*2 + i] : zs[((size_t)b*2048+n)*64 + (i-2)];
      else      v = (i<2) ? c1x[((size_t)b*2048+n)*2 + i] : c2s[((size_t)b*2048+n)*64 + (i-2)];
      xg4[bi][k][i] = v;
    }
    __syncthreads();
    {
      int bi = t>>6, o = t&63, b = bb*4 + bi;
      float a = 0.f;
      #pragma unroll
      for (int k=0;k<2;k++)
        for (int i=0;i<66;i++) a += xg4[bi][k][i]*Wn[k][i][o];
      float hc = tanhf(a + bnu[o]);
      float rv = rws[((size_t)b*2048+n)*64 + o];
      h[((size_t)b*2048+n)*64 + o] = rv*state[((size_t)b*2048+n)*64 + o] + (1.f - rv)*hc;
    }
    __syncthreads();
  }
}

// ---------------------------------------------------------------------------
// K5: fused degrees, fp8 MFMA, software-pipelined (half-group rolling loads).
// 1D grid 2048 blocks, 512 threads. mask = (id>>2)&1 (XCD-stable), b = high bits.
// LDS: S fp8 [32][2056] dynamic (65,792 B). Scaling: S/8, 16W, deg*256.
// ---------------------------------------------------------------------------
#define SROW8 2056

__global__ void __launch_bounds__(512,2) k_deg(
    const u32* __restrict__ mp2, const u32* __restrict__ mn2,
    const u16* __restrict__ hb16,
    const u8* __restrict__ Wc8, const u8* __restrict__ Wd8,
    const u8* __restrict__ ht8p, const u16* __restrict__ hfm,
    float* __restrict__ outc, float* __restrict__ outd){
  extern __shared__ u8 S[];
  __shared__ float redm[32][8];
  __shared__ float redsum[32][8];
  const int t = threadIdx.x;
  const int w = t >> 6, lane = t & 63, lc = lane & 15, q = lane >> 4;
  const int id = blockIdx.x;
  const int mask = (id >> 2) & 1;
  const int sub = ((id & 3) << 8) | (id >> 3);     // 0..1023
  const int b = sub >> 6, n0 = (sub & 63) * 32;    // co-resident blocks share b
  const u8* W8 = mask ? Wd8 : Wc8;
  const u32* mrow = (mask ? mn2 : mp2) + (size_t)(n0 >> 5)*2048;
  const u16* hbb = hb16 + (size_t)b*2048*64;
  const u16* hfb = hfm + (size_t)b*131072;
  const u8* htb = ht8p + (size_t)b*131072;

  // ---- phase 1: S[r][m] = fp8( (bit ? h_n.h_m : 0) / 8 ), pipelined ----
  {
    bf16x8 A[2][2];
    #pragma unroll
    for (int rt=0; rt<2; ++rt)
      #pragma unroll
      for (int ks=0; ks<2; ++ks)
        A[rt][ks] = *(const bf16x8*)&hbb[(size_t)(n0 + rt*16 + lc)*64 + ks*32 + q*8];
    int ctg0 = w*16;
    bf16x8 B0c = *(const bf16x8*)(hfb + (size_t)ctg0*512 + lane*8);
    bf16x8 B1c = *(const bf16x8*)(hfb + 65536 + (size_t)ctg0*512 + lane*8);
    u32 mbc = mrow[ctg0*16 + lc];
    #pragma unroll 1
    for (int ct=0; ct<16; ++ct){
      const int ctg = w*16 + ct;
      const int ctgn = w*16 + ((ct+1) & 15);
      bf16x8 B0n = *(const bf16x8*)(hfb + (size_t)ctgn*512 + lane*8);
      bf16x8 B1n = *(const bf16x8*)(hfb + 65536 + (size_t)ctgn*512 + lane*8);
      u32 mbn = mrow[ctgn*16 + lc];
      const int mcol = ctg*16 + lc;
      f32x4 a0 = {0.f,0.f,0.f,0.f}, a1 = {0.f,0.f,0.f,0.f};
      a0 = mfma_bf16(A[0][0], B0c, a0); a0 = mfma_bf16(A[0][1], B1c, a0);
      a1 = mfma_bf16(A[1][0], B0c, a1); a1 = mfma_bf16(A[1][1], B1c, a1);
      #pragma unroll
      for (int i=0;i<4;i++){
        int r0 = q*4 + i, r1 = 16 + q*4 + i;
        float v0 = ((mbc >> r0) & 1u) ? a0[i]*0.125f : 0.f;
        float v1 = ((mbc >> r1) & 1u) ? a1[i]*0.125f : 0.f;
        S[r0*SROW8 + mcol] = f2fp8(v0);
        S[r1*SROW8 + mcol] = f2fp8(v1);
      }
      B0c = B0n; B1c = B1n; mbc = mbn;
    }
  }
  __syncthreads();

  // ---- phase 2: logits = S @ W ; wave owns k-cols [w*256, w*256+256) ----
  // Half-group rolling prefetch: 8 uint4 in flight + 8 in use (no reg growth).
  f32x4 acc0[16], acc1[16];
  #pragma unroll
  for (int ct=0;ct<16;ct++){ acc0[ct] = (f32x4){0.f,0.f,0.f,0.f}; acc1[ct] = (f32x4){0.f,0.f,0.f,0.f}; }
  {
    const u8* wbase = W8 + (size_t)(w*16)*1024 + lane*16;
    uint4 bv[8];
    #pragma unroll
    for (int ct=0; ct<8; ++ct) bv[ct] = *(const uint4*)(wbase + ct*1024);
    #pragma unroll 1
    for (int pt=0; pt<32; ++pt){
      const u8* sp0 = S + lc*SROW8 + q*8 + pt*64;
      long a0e = *(const long*)(sp0);
      long a0o = *(const long*)(sp0 + 32);
      long a1e = *(const long*)(sp0 + 16*SROW8);
      long a1o = *(const long*)(sp0 + 16*SROW8 + 32);
      const u8* wcur = wbase + (size_t)pt*131072;
      const u8* wnxt = wbase + (size_t)((pt+1)&31)*131072;
      uint4 bw[8];
      #pragma unroll
      for (int ct=0; ct<8; ++ct) bw[ct] = *(const uint4*)(wcur + (8+ct)*1024);
      #pragma unroll
      for (int ct=0; ct<8; ++ct){
        long be = lo64(bv[ct]), bo = hi64(bv[ct]);
        acc0[ct] = mfma_fp8(a0e, be, acc0[ct]);
        acc1[ct] = mfma_fp8(a1e, be, acc1[ct]);
        acc0[ct] = mfma_fp8(a0o, bo, acc0[ct]);
        acc1[ct] = mfma_fp8(a1o, bo, acc1[ct]);
      }
      #pragma unroll
      for (int ct=0; ct<8; ++ct) bv[ct] = *(const uint4*)(wnxt + ct*1024);
      #pragma unroll
      for (int ct=0; ct<8; ++ct){
        long be = lo64(bw[ct]), bo = hi64(bw[ct]);
        acc0[8+ct] = mfma_fp8(a0e, be, acc0[8+ct]);
        acc1[8+ct] = mfma_fp8(a1e, be, acc1[8+ct]);
        acc0[8+ct] = mfma_fp8(a0o, bo, acc0[8+ct]);
        acc1[8+ct] = mfma_fp8(a1o, bo, acc1[8+ct]);
      }
    }
  }

  // ---- phase 3: row softmax over k (true logits = 0.5*acc) ----
  float gmax0[4], gmax1[4], gsc0[4], gsc1[4];
  #pragma unroll
  for (int i=0;i<4;i++){
    float mx0 = acc0[0][i], mx1 = acc1[0][i];
    #pragma unroll
    for (int ct=1; ct<16; ++ct){ mx0 = fmaxf(mx0, acc0[ct][i]); mx1 = fmaxf(mx1, acc1[ct][i]); }
    mx0 = fmaxf(mx0, __shfl_xor(mx0, 1)); mx1 = fmaxf(mx1, __shfl_xor(mx1, 1));
    mx0 = fmaxf(mx0, __shfl_xor(mx0, 2)); mx1 = fmaxf(mx1, __shfl_xor(mx1, 2));
    mx0 = fmaxf(mx0, __shfl_xor(mx0, 4)); mx1 = fmaxf(mx1, __shfl_xor(mx1, 4));
    mx0 = fmaxf(mx0, __shfl_xor(mx0, 8)); mx1 = fmaxf(mx1, __shfl_xor(mx1, 8));
    if (lc == 0){ redm[q*4+i][w] = mx0; redm[16+q*4+i][w] = mx1; }
  }
  __syncthreads();
  #pragma unroll
  for (int i=0;i<4;i++){
    float m0 = redm[q*4+i][0], m1 = redm[16+q*4+i][0];
    #pragma unroll
    for (int j=1;j<8;j++){ m0 = fmaxf(m0, redm[q*4+i][j]); m1 = fmaxf(m1, redm[16+q*4+i][j]); }
    gmax0[i] = m0; gmax1[i] = m1;
  }
  #pragma unroll
  for (int i=0;i<4;i++){
    float s0 = 0.f, s1 = 0.f;
    #pragma unroll
    for (int ct=0; ct<16; ++ct){
      float e0 = __expf(0.5f*(acc0[ct][i] - gmax0[i]));
      float e1 = __expf(0.5f*(acc1[ct][i] - gmax1[i]));
      acc0[ct][i] = e0; acc1[ct][i] = e1;
      s0 += e0; s1 += e1;
    }
    s0 += __shfl_xor(s0, 1); s1 += __shfl_xor(s1, 1);
    s0 += __shfl_xor(s0, 2); s1 += __shfl_xor(s1, 2);
    s0 += __shfl_xor(s0, 4); s1 += __shfl_xor(s1, 4);
    s0 += __shfl_xor(s0, 8); s1 += __shfl_xor(s1, 8);
    if (lc == 0){ redsum[q*4+i][w] = s0; redsum[16+q*4+i][w] = s1; }
  }
  __syncthreads();
  #pragma unroll
  for (int i=0;i<4;i++){
    float s0 = 0.f, s1 = 0.f;
    #pragma unroll
    for (int j=0;j<8;j++){ s0 += redsum[q*4+i][j]; s1 += redsum[16+q*4+i][j]; }
    gsc0[i] = 256.f/s0; gsc1[i] = 256.f/s1;
  }
  #pragma unroll
  for (int ct=0; ct<16; ++ct){
    const int col = w*256 + ct*16 + lc;
    #pragma unroll
    for (int i=0;i<4;i++){
      S[(q*4+i)*SROW8 + col]      = f2fp8(acc0[ct][i]*gsc0[i]);
      S[(16+q*4+i)*SROW8 + col]   = f2fp8(acc1[ct][i]*gsc1[i]);
    }
  }
  __syncthreads();

  // ---- phase 4: out = (deg*256) @ h / 256, pipelined ----
  {
    const int rt4 = w >> 2, dt = w & 3;
    f32x4 o = {0.f,0.f,0.f,0.f};
    const u8* abase = S + (size_t)(rt4*16 + lc)*SROW8 + q*8;
    const u8* bbase = htb + (size_t)dt*1024 + lane*16;
    uint4 bcur = *(const uint4*)(bbase);
    #pragma unroll 1
    for (int pt=0; pt<32; ++pt){
      uint4 bnxt = *(const uint4*)(bbase + (size_t)((pt+1)&31)*4096);
      long ae = *(const long*)(abase + pt*64);
      long ao = *(const long*)(abase + pt*64 + 32);
      o = mfma_fp8(ae, lo64(bcur), o);
      o = mfma_fp8(ao, hi64(bcur), o);
      bcur = bnxt;
    }
    float* op = (mask ? outd : outc) + (size_t)b*2048*64;
    #pragma unroll
    for (int i=0;i<4;i++)
      op[(size_t)(n0 + rt4*16 + q*4 + i)*64 + dt*16 + lc] = o[i]*(1.f/256.f);
  }
}

// ---------------------------------------------------------------------------
// K6: numerator = 0.8h - 0.1 outc + 0.1 outd  -> f32 output
// ---------------------------------------------------------------------------
__global__ void k_final(const float* __restrict__ h, const float* __restrict__ outc,
                        const float* __restrict__ outd, float* __restrict__ out){
  size_t i = (size_t)blockIdx.x*256 + threadIdx.x;
  out[i] = 0.8f*h[i] - 0.1f*outc[i] + 0.1f*outd[i];
}

// ---------------------------------------------------------------------------
extern "C" void kernel_launch(void* const* d_in, const int* in_sizes, int n_in,
                              void* d_out, int out_size, void* d_ws, size_t ws_size,
                              hipStream_t stream) {
  const float* x     = (const float*)d_in[0];
  const float* state = (const float*)d_in[1];
  const float* E     = (const float*)d_in[2];
  const float* Wc    = (const float*)d_in[3];
  const float* Wd    = (const float*)d_in[4];
  const float* gw    = (const float*)d_in[5];
  const float* gb    = (const float*)d_in[6];
  const float* uw    = (const float*)d_in[7];
  const float* ub    = (const float*)d_in[8];

  // workspace layout (bytes). Total 73,662,464 B = 70.2 MB (same as round 6).
  char* base = (char*)d_ws;
  u16*   P    = (u16*)(base + 0);           //  8,388,608  (dead after 2nd k_conv)
  u32*   mp2  = (u32*)(base + 0);           //    524,288  (aliases P; written after P dead)
  u32*   mn2  = (u32*)(base + 524288);      //    524,288  (aliases P)
  u8*    msk  = (u8*) (base + 8388608);     //  4,194,304
  u8*    Wc8  = (u8*) (base + 12582912);    //  4,194,304
  u8*    Wd8  = (u8*) (base + 16777216);    //  4,194,304
  u16*   hb16 = (u16*)(base + 20971520);    //  4,194,304
  u8*    ht8p = (u8*) (base + 25165824);    //  2,097,152
  u16*   hfm  = (u16*)(base + 27262976);    //  4,194,304
  float* c1x  = (float*)(base + 31457280);  //    262,144
  float* c1s  = (float*)(base + 31719424);  //  8,388,608
  float* zs   = (float*)(base + 40108032);  //  8,388,608
  float* rws  = (float*)(base + 48496640);  //  8,388,608
  float* c2s  = (float*)(base + 56885248);  //  8,388,608
  float* h    = (float*)(base + 65273856);  //  8,388,608
  float* oc   = c1s;                        // dead after k_gate
  float* od   = c2s;                        // dead after k_upd

  k_w8<<<dim3(32,32,2), 256, 0, stream>>>(Wc, Wd, Wc8, Wd8);
  k_P<<<2048, 256, 0, stream>>>(E, P, msk);
  k_c1x<<<dim3(32,16), 128, 0, stream>>>(P, x, c1x);
  k_conv<<<dim3(32,16), 256, 0, stream>>>(P, state, c1s);
  k_gate<<<2048, 256, 0, stream>>>(E, gw, gb, x, state, c1x, c1s, zs, rws);
  k_conv<<<dim3(32,16), 256, 0, stream>>>(P, zs, c2s);
  k_upd<<<2048, 256, 0, stream>>>(E, uw, ub, x, state, zs, c1x, c2s, rws, h);
  k_hcvt<<<dim3(32,16), 256, 0, stream>>>(h, hb16, ht8p, hfm);
  k_mbits<<<dim3(2048,8), 256, 0, stream>>>(msk, mp2, mn2);   // P dead by now

  const int deg_lds = 32*SROW8;   // 65,792 B dynamic
  hipFuncSetAttribute((const void*)k_deg, hipFuncAttributeMaxDynamicSharedMemorySize, deg_lds);
  k_deg<<<2048, 512, deg_lds, stream>>>(mp2, mn2, hb16, Wc8, Wd8, ht8p, hfm, oc, od);

  k_final<<<8192, 256, 0, stream>>>(h, oc, od, (float*)d_out);
}

// Round 8
// 2304.415 us; speedup vs baseline: 3.5643x; 1.0037x over previous
//
#include <hip/hip_runtime.h>
#include <hip/hip_bf16.h>

typedef unsigned short u16;
typedef unsigned int   u32;
typedef unsigned char  u8;

typedef __attribute__((ext_vector_type(8))) short bf16x8;
typedef __attribute__((ext_vector_type(4))) float f32x4;

static __device__ __forceinline__ float bf2f(u16 u){ return __uint_as_float(((u32)u)<<16); }
static __device__ __forceinline__ u16 f2bf(float f){
  u32 u = __float_as_uint(f);
  u32 r = (u + 0x7fff + ((u>>16)&1)) >> 16;   // RNE; inputs finite
  return (u16)r;
}

// fp8 e4m3 (OCP) helpers — HW cvt, saturating via pre-clamp
static __device__ __forceinline__ u8 f2fp8(float v){
  v = fminf(440.f, fmaxf(-440.f, v));
  return (u8)(__builtin_amdgcn_cvt_pk_fp8_f32(v, 0.f, 0, false) & 0xff);
}
static __device__ __forceinline__ u32 pk4_fp8(float a, float b, float c, float d){
  int w = __builtin_amdgcn_cvt_pk_fp8_f32(a, b, 0, false);
  w = __builtin_amdgcn_cvt_pk_fp8_f32(c, d, w, true);
  return (u32)w;
}

static __device__ __forceinline__ f32x4 mfma_bf16(bf16x8 a, bf16x8 b, f32x4 c){
  return __builtin_amdgcn_mfma_f32_16x16x32_bf16(a, b, c, 0, 0, 0);
}
static __device__ __forceinline__ f32x4 mfma_fp8(long a, long b, f32x4 c){
  return __builtin_amdgcn_mfma_f32_16x16x32_fp8_fp8(a, b, c, 0, 0, 0);
}
static __device__ __forceinline__ long lo64(uint4 v){ return (long)(((unsigned long long)v.y<<32) | v.x); }
static __device__ __forceinline__ long hi64(uint4 v){ return (long)(((unsigned long long)v.w<<32) | v.z); }

// ---------------------------------------------------------------------------
// K-w8: W f32 [m][k] -> fragment-major fp8 (16*W), 1KB-contiguous per (pt,ctg).
// grid (32,32,2), block 256.
// ---------------------------------------------------------------------------
__global__ void k_w8(const float* __restrict__ Wc, const float* __restrict__ Wd,
                     u8* __restrict__ Wc8, u8* __restrict__ Wd8){
  __shared__ float tile[64][65];
  const float* src = blockIdx.z ? Wd : Wc;
  u8* dst = blockIdx.z ? Wd8 : Wc8;
  const int m0 = blockIdx.x*64, k0 = blockIdx.y*64;
  const int t = threadIdx.x, r = t & 63, cc = t >> 6;
  #pragma unroll
  for (int j=0;j<4;j++){
    float4 v = *(const float4*)&src[(size_t)(m0+r)*2048 + k0 + cc*16 + j*4];
    tile[r][cc*16+j*4+0]=v.x; tile[r][cc*16+j*4+1]=v.y;
    tile[r][cc*16+j*4+2]=v.z; tile[r][cc*16+j*4+3]=v.w;
  }
  __syncthreads();
  u32 f0 = pk4_fp8(16.f*tile[cc*16+ 0][r], 16.f*tile[cc*16+ 1][r], 16.f*tile[cc*16+ 2][r], 16.f*tile[cc*16+ 3][r]);
  u32 f1 = pk4_fp8(16.f*tile[cc*16+ 4][r], 16.f*tile[cc*16+ 5][r], 16.f*tile[cc*16+ 6][r], 16.f*tile[cc*16+ 7][r]);
  u32 f2 = pk4_fp8(16.f*tile[cc*16+ 8][r], 16.f*tile[cc*16+ 9][r], 16.f*tile[cc*16+10][r], 16.f*tile[cc*16+11][r]);
  u32 f3 = pk4_fp8(16.f*tile[cc*16+12][r], 16.f*tile[cc*16+13][r], 16.f*tile[cc*16+14][r], 16.f*tile[cc*16+15][r]);
  const int k = k0 + r, mbase = m0 + cc*16;
  const int pt = mbase >> 6, half = (mbase >> 5) & 1, q0 = (mbase >> 3) & 3;
  const int ctg = k >> 4, lcv = k & 15;
  u8* dbase = dst + (size_t)((pt*128 + ctg)*64)*16 + half*8;
  *(uint2*)(dbase + (q0*16 + lcv)*16)     = make_uint2(f0, f1);
  *(uint2*)(dbase + ((q0+1)*16 + lcv)*16) = make_uint2(f2, f3);
}

// ---------------------------------------------------------------------------
// K-hcvt: h f32 [b][m][64] -> hb16 (bf16 row-major), hfm (bf16 frag-major B for
// phase 1), ht8p (fp8 frag-major B for phase 4). grid (32,16), block 256.
// ---------------------------------------------------------------------------
__global__ void k_hcvt(const float* __restrict__ h, u16* __restrict__ hb16,
                       u8* __restrict__ ht8p, u16* __restrict__ hfm){
  __shared__ float tile[64][65];
  const int k0 = blockIdx.x*64, b = blockIdx.y;
  const int t = threadIdx.x, r = t & 63, cc = t >> 6;
  const float* src = h + ((size_t)b*2048 + k0)*64;
  u32 hw[8];
  #pragma unroll
  for (int j=0;j<4;j++){
    float4 v = *(const float4*)&src[(size_t)r*64 + cc*16 + j*4];
    tile[r][cc*16+j*4+0]=v.x; tile[r][cc*16+j*4+1]=v.y;
    tile[r][cc*16+j*4+2]=v.z; tile[r][cc*16+j*4+3]=v.w;
    hw[2*j]   = (u32)f2bf(v.x) | ((u32)f2bf(v.y)<<16);
    hw[2*j+1] = (u32)f2bf(v.z) | ((u32)f2bf(v.w)<<16);
  }
  u16* hp = hb16 + (((size_t)b*2048 + k0 + r)*64 + cc*16);
  *(uint4*)hp     = make_uint4(hw[0],hw[1],hw[2],hw[3]);
  *(uint4*)(hp+8) = make_uint4(hw[4],hw[5],hw[6],hw[7]);
  __syncthreads();
  {
    u32 f0 = pk4_fp8(tile[cc*16+ 0][r], tile[cc*16+ 1][r], tile[cc*16+ 2][r], tile[cc*16+ 3][r]);
    u32 f1 = pk4_fp8(tile[cc*16+ 4][r], tile[cc*16+ 5][r], tile[cc*16+ 6][r], tile[cc*16+ 7][r]);
    u32 f2 = pk4_fp8(tile[cc*16+ 8][r], tile[cc*16+ 9][r], tile[cc*16+10][r], tile[cc*16+11][r]);
    u32 f3 = pk4_fp8(tile[cc*16+12][r], tile[cc*16+13][r], tile[cc*16+14][r], tile[cc*16+15][r]);
    const int pt = k0 >> 6, half = cc >> 1, q0 = (cc & 1)*2;
    const int ctg = r >> 4, lcv = r & 15;
    u8* dbase = ht8p + (size_t)b*131072 + (size_t)((pt*4 + ctg)*64)*16 + half*8;
    *(uint2*)(dbase + (q0*16 + lcv)*16)     = make_uint2(f0, f1);
    *(uint2*)(dbase + ((q0+1)*16 + lcv)*16) = make_uint2(f2, f3);
  }
  {
    const int col = k0 + r, ks = cc >> 1, q0 = (cc & 1)*2;
    const int ctg = col >> 4, lcv = col & 15;
    u16* fbase = hfm + (size_t)b*131072 + (size_t)ks*65536 + ((size_t)ctg*64)*8;
    #pragma unroll
    for (int qq=0; qq<2; ++qq){
      int q = q0 + qq;
      u32 p0 = (u32)f2bf(tile[r][ks*32+q*8+0]) | ((u32)f2bf(tile[r][ks*32+q*8+1])<<16);
      u32 p1 = (u32)f2bf(tile[r][ks*32+q*8+2]) | ((u32)f2bf(tile[r][ks*32+q*8+3])<<16);
      u32 p2 = (u32)f2bf(tile[r][ks*32+q*8+4]) | ((u32)f2bf(tile[r][ks*32+q*8+5])<<16);
      u32 p3 = (u32)f2bf(tile[r][ks*32+q*8+6]) | ((u32)f2bf(tile[r][ks*32+q*8+7])<<16);
      *(uint4*)(fbase + (size_t)(q*16 + lcv)*8) = make_uint4(p0,p1,p2,p3);
    }
  }
}

// ---------------------------------------------------------------------------
// K1: row n of A = E E^T. sign-mask (1 pos, 2 neg) + P=softmax(relu) bf16.
// ---------------------------------------------------------------------------
__global__ void k_P(const float* __restrict__ E, u16* __restrict__ P, u8* __restrict__ msk){
  __shared__ float Ew[16];
  __shared__ float arow[2048];
  __shared__ float red[4];
  const int t = threadIdx.x, n = blockIdx.x;
  if (t < 16) Ew[t] = E[n*16 + t];
  __syncthreads();
  float lmax = 0.f;
  for (int i=0;i<8;i++){
    int m = t + 256*i;
    const float* ep = E + m*16;
    float dot = 0.f;
    #pragma unroll
    for (int d=0; d<16; ++d) dot += Ew[d]*ep[d];
    msk[n*2048 + m] = dot > 0.f ? (u8)1 : (dot < 0.f ? (u8)2 : (u8)0);
    float ar = fmaxf(dot, 0.f);
    arow[m] = ar;
    lmax = fmaxf(lmax, ar);
  }
  for (int o=1;o<64;o<<=1) lmax = fmaxf(lmax, __shfl_xor(lmax, o));
  if ((t&63)==0) red[t>>6] = lmax;
  __syncthreads();
  float gmax = fmaxf(fmaxf(red[0],red[1]), fmaxf(red[2],red[3]));
  __syncthreads();
  float lsum = 0.f;
  for (int i=0;i<8;i++){
    int m = t + 256*i;
    float e = expf(arow[m] - gmax);
    arow[m] = e;
    lsum += e;
  }
  for (int o=1;o<64;o<<=1) lsum += __shfl_xor(lsum, o);
  if ((t&63)==0) red[t>>6] = lsum;
  __syncthreads();
  float inv = 1.f/(red[0]+red[1]+red[2]+red[3]);
  for (int i=0;i<8;i++){
    int m = t + 256*i;
    P[n*2048 + m] = f2bf(arow[m]*inv);
  }
}

// ---------------------------------------------------------------------------
// K-mbits: msk u8 [n][m] -> transposed bitmaps mp2/mn2 u32 [n/32][m].
// grid (2048, 8), block 256.
// ---------------------------------------------------------------------------
__global__ void k_mbits(const u8* __restrict__ msk, u32* __restrict__ mp2, u32* __restrict__ mn2){
  const int m = blockIdx.x, nb = blockIdx.y*256;
  const int t = threadIdx.x, w = t>>6, lane = t&63;
  u8 v = msk[(size_t)(nb + t)*2048 + m];
  unsigned long long bp = __ballot(v == (u8)1);
  unsigned long long bn = __ballot(v == (u8)2);
  if (lane == 0){
    int wi = (nb + w*64) >> 5;
    mp2[(size_t)wi*2048 + m]     = (u32)bp;
    mp2[(size_t)(wi+1)*2048 + m] = (u32)(bp>>32);
    mn2[(size_t)wi*2048 + m]     = (u32)bn;
    mn2[(size_t)(wi+1)*2048 + m] = (u32)(bn>>32);
  }
}

// ---------------------------------------------------------------------------
// K2x: c1x[b,n,c] = sum_m P[n,m] * x[b,m,c]
// ---------------------------------------------------------------------------
__global__ void k_c1x(const u16* __restrict__ P, const float* __restrict__ x, float* __restrict__ c1x){
  const int t = threadIdx.x;
  const int r = t>>1, c = t&1;
  const int n = blockIdx.x*64 + r, b = blockIdx.y;
  const u16* pr = P + (size_t)n*2048;
  const float* xb = x + (size_t)b*2048*2 + c;
  float acc = 0.f;
  for (int m=0;m<2048;m+=4){
    acc += bf2f(pr[m+0])*xb[(m+0)*2];
    acc += bf2f(pr[m+1])*xb[(m+1)*2];
    acc += bf2f(pr[m+2])*xb[(m+2)*2];
    acc += bf2f(pr[m+3])*xb[(m+3)*2];
  }
  c1x[((size_t)b*2048 + n)*2 + c] = acc;
}

// ---------------------------------------------------------------------------
// K2: Y[b,n,d] = sum_m P[n,m] * Z[b,m,d], Z f32 [B,N,64]. 64x64 tile.
// ---------------------------------------------------------------------------
__global__ void k_conv(const u16* __restrict__ P, const float* __restrict__ Z, float* __restrict__ Y){
  __shared__ float Pt[16][68];
  __shared__ float Zt[16][68];
  const int t = threadIdx.x;
  const int tr = t>>4, tc = t&15;
  const int n0 = blockIdx.x*64, b = blockIdx.y;
  float acc[4][4] = {};
  for (int mt=0; mt<128; ++mt){
    int m0 = mt*16;
    {
      int r = t>>2, c4 = (t&3)*4;
      const u16* pp = P + (size_t)(n0+r)*2048 + m0 + c4;
      u32 p0 = *(const u32*)pp, p1v = *(const u32*)(pp+2);
      Pt[c4+0][r]=bf2f((u16)p0);  Pt[c4+1][r]=bf2f((u16)(p0>>16));
      Pt[c4+2][r]=bf2f((u16)p1v); Pt[c4+3][r]=bf2f((u16)(p1v>>16));
      int mm = t>>4, d0 = (t&15)*4;
      float4 zv = *(const float4*)&Z[((size_t)b*2048 + m0+mm)*64 + d0];
      Zt[mm][d0+0]=zv.x; Zt[mm][d0+1]=zv.y; Zt[mm][d0+2]=zv.z; Zt[mm][d0+3]=zv.w;
    }
    __syncthreads();
    #pragma unroll
    for (int mm=0; mm<16; ++mm){
      float4 a  = *(const float4*)&Pt[mm][tr*4];
      float4 bz = *(const float4*)&Zt[mm][tc*4];
      acc[0][0]+=a.x*bz.x; acc[0][1]+=a.x*bz.y; acc[0][2]+=a.x*bz.z; acc[0][3]+=a.x*bz.w;
      acc[1][0]+=a.y*bz.x; acc[1][1]+=a.y*bz.y; acc[1][2]+=a.y*bz.z; acc[1][3]+=a.y*bz.w;
      acc[2][0]+=a.z*bz.x; acc[2][1]+=a.z*bz.y; acc[2][2]+=a.z*bz.z; acc[2][3]+=a.z*bz.w;
      acc[3][0]+=a.w*bz.x; acc[3][1]+=a.w*bz.y; acc[3][2]+=a.w*bz.z; acc[3][3]+=a.w*bz.w;
    }
    __syncthreads();
  }
  #pragma unroll
  for (int i=0;i<4;i++){
    float4 v = make_float4(acc[i][0],acc[i][1],acc[i][2],acc[i][3]);
    *(float4*)&Y[((size_t)b*2048 + n0 + tr*4 + i)*64 + tc*4] = v;
  }
}

// ---------------------------------------------------------------------------
// K3: gate SAGC -> zs = z*state, rws = r. One block per node n.
// ---------------------------------------------------------------------------
__global__ void k_gate(const float* __restrict__ E, const float* __restrict__ gw, const float* __restrict__ gb,
                       const float* __restrict__ x, const float* __restrict__ state,
                       const float* __restrict__ c1x, const float* __restrict__ c1s,
                       float* __restrict__ zs, float* __restrict__ rws){
  __shared__ float Ew[16];
  __shared__ float bnv[128];
  __shared__ float Wn[2][66][64];
  __shared__ float xg4[4][2][66];
  const int t = threadIdx.x, n = blockIdx.x;
  if (t < 16) Ew[t] = E[n*16 + t];
  __syncthreads();
  if (t < 128){
    float a = 0.f;
    #pragma unroll
    for (int e=0;e<16;e++) a += Ew[e]*gb[e*128 + t];
    bnv[t] = a;
  }
  for (int half=0; half<2; ++half){
    for (int idx=t; idx<8448; idx+=256){
      int o = idx & 63, rest = idx>>6, i = rest % 66, k = rest / 66;
      float a = 0.f;
      #pragma unroll
      for (int e=0;e<16;e++) a += Ew[e]*gw[((e*2+k)*66 + i)*128 + half*64 + o];
      Wn[k][i][o] = a;
    }
    __syncthreads();
    for (int bb=0; bb<4; ++bb){
      for (int idx=t; idx<528; idx+=256){
        int bi = idx/132, rem = idx%132, k = rem/66, i = rem%66;
        int b = bb*4 + bi;
        float v;
        if (k==0) v = (i<2) ? x[((size_t)b*2048+n)*2 + i] : state[((size_t)b*2048+n)*64 + (i-2)];
        else      v = (i<2) ? c1x[((size_t)b*2048+n)*2 + i] : c1s[((size_t)b*2048+n)*64 + (i-2)];
        xg4[bi][k][i] = v;
      }
      __syncthreads();
      {
        int bi = t>>6, o = t&63, b = bb*4 + bi;
        float a = 0.f;
        #pragma unroll
        for (int k=0;k<2;k++)
          for (int i=0;i<66;i++) a += xg4[bi][k][i]*Wn[k][i][o];
        a += bnv[half*64 + o];
        float s = 1.f/(1.f + expf(-a));
        if (half==0) zs[((size_t)b*2048+n)*64 + o] = s*state[((size_t)b*2048+n)*64 + o];
        else         rws[((size_t)b*2048+n)*64 + o] = s;
      }
      __syncthreads();
    }
  }
}

// ---------------------------------------------------------------------------
// K3b: update SAGC -> hc -> h = r*state + (1-r)*hc.
// ---------------------------------------------------------------------------
__global__ void k_upd(const float* __restrict__ E, const float* __restrict__ uw, const float* __restrict__ ub,
                      const float* __restrict__ x, const float* __restrict__ state,
                      const float* __restrict__ zs, const float* __restrict__ c1x, const float* __restrict__ c2s,
                      const float* __restrict__ rws, float* __restrict__ h){
  __shared__ float Ew[16];
  __shared__ float bnu[64];
  __shared__ float Wn[2][66][64];
  __shared__ float xg4[4][2][66];
  const int t = threadIdx.x, n = blockIdx.x;
  if (t < 16) Ew[t] = E[n*16 + t];
  __syncthreads();
  if (t < 64){
    float a = 0.f;
    #pragma unroll
    for (int e=0;e<16;e++) a += Ew[e]*ub[e*64 + t];
    bnu[t] = a;
  }
  for (int idx=t; idx<8448; idx+=256){
    int o = idx & 63, rest = idx>>6, i = rest % 66, k = rest / 66;
    float a = 0.f;
    #pragma unroll
    for (int e=0;e<16;e++) a += Ew[e]*uw[((e*2+k)*66 + i)*64 + o];
    Wn[k][i][o] = a;
  }
  __syncthreads();
  for (int bb=0; bb<4; ++bb){
    for (int idx=t; idx<528; idx+=256){
      int bi = idx/132, rem = idx%132, k = rem/66, i = rem%66;
      int b = bb*4 + bi;
      float v;
      if (k==0) v = (i<2) ? x[((size_t)b*2048+n)*2 + i] : zs[((size_t)b*2048+n)*64 + (i-2)];
      else      v = (i<2) ? c1x[((size_t)b*2048+n)*2 + i] : c2s[((size_t)b*2048+n)*64 + (i-2)];
      xg4[bi][k][i] = v;
    }
    __syncthreads();
    {
      int bi = t>>6, o = t&63, b = bb*4 + bi;
      float a = 0.f;
      #pragma unroll
      for (int k=0;k<2;k++)
        for (int i=0;i<66;i++) a += xg4[bi][k][i]*Wn[k][i][o];
      float hc = tanhf(a + bnu[o]);
      float rv = rws[((size_t)b*2048+n)*64 + o];
      h[((size_t)b*2048+n)*64 + o] = rv*state[((size_t)b*2048+n)*64 + o] + (1.f - rv)*hc;
    }
    __syncthreads();
  }
}

// ---------------------------------------------------------------------------
// K5: fused degrees, fp8 MFMA — ONE MASK PER DISPATCH (temporal W partitioning:
// during each dispatch every XCD L2 holds only one 4 MB W). grid 1024, 512 thr.
// fin=1: epilogue computes final output 0.8h - 0.1 oc + 0.1 od -> outp.
// LDS: S fp8 [32][2056] dynamic (65,792 B). Scaling: S/8, 16W, deg*256.
// ---------------------------------------------------------------------------
#define SROW8 2056

__global__ void __launch_bounds__(512,2) k_deg(
    const u32* __restrict__ mbits, const u16* __restrict__ hb16,
    const u8* __restrict__ W8,
    const u8* __restrict__ ht8p, const u16* __restrict__ hfm,
    const float* __restrict__ hf32, const float* __restrict__ oc_in,
    float* __restrict__ outp, int fin){
  extern __shared__ u8 S[];
  __shared__ float redm[32][8];
  __shared__ float redsum[32][8];
  const int t = threadIdx.x;
  const int w = t >> 6, lane = t & 63, lc = lane & 15, q = lane >> 4;
  const int id = blockIdx.x;
  const int b = id >> 6, n0 = (id & 63) * 32;
  const u32* mrow = mbits + (size_t)(n0 >> 5)*2048;
  const u16* hbb = hb16 + (size_t)b*2048*64;
  const u16* hfb = hfm + (size_t)b*131072;
  const u8* htb = ht8p + (size_t)b*131072;

  // ---- phase 1: S[r][m] = fp8( (bit ? h_n.h_m : 0) / 8 ), pipelined ----
  {
    bf16x8 A[2][2];
    #pragma unroll
    for (int rt=0; rt<2; ++rt)
      #pragma unroll
      for (int ks=0; ks<2; ++ks)
        A[rt][ks] = *(const bf16x8*)&hbb[(size_t)(n0 + rt*16 + lc)*64 + ks*32 + q*8];
    int ctg0 = w*16;
    bf16x8 B0c = *(const bf16x8*)(hfb + (size_t)ctg0*512 + lane*8);
    bf16x8 B1c = *(const bf16x8*)(hfb + 65536 + (size_t)ctg0*512 + lane*8);
    u32 mbc = mrow[ctg0*16 + lc];
    #pragma unroll 1
    for (int ct=0; ct<16; ++ct){
      const int ctg = w*16 + ct;
      const int ctgn = w*16 + ((ct+1) & 15);
      bf16x8 B0n = *(const bf16x8*)(hfb + (size_t)ctgn*512 + lane*8);
      bf16x8 B1n = *(const bf16x8*)(hfb + 65536 + (size_t)ctgn*512 + lane*8);
      u32 mbn = mrow[ctgn*16 + lc];
      const int mcol = ctg*16 + lc;
      f32x4 a0 = {0.f,0.f,0.f,0.f}, a1 = {0.f,0.f,0.f,0.f};
      a0 = mfma_bf16(A[0][0], B0c, a0); a0 = mfma_bf16(A[0][1], B1c, a0);
      a1 = mfma_bf16(A[1][0], B0c, a1); a1 = mfma_bf16(A[1][1], B1c, a1);
      #pragma unroll
      for (int i=0;i<4;i++){
        int r0 = q*4 + i, r1 = 16 + q*4 + i;
        float v0 = ((mbc >> r0) & 1u) ? a0[i]*0.125f : 0.f;
        float v1 = ((mbc >> r1) & 1u) ? a1[i]*0.125f : 0.f;
        S[r0*SROW8 + mcol] = f2fp8(v0);
        S[r1*SROW8 + mcol] = f2fp8(v1);
      }
      B0c = B0n; B1c = B1n; mbc = mbn;
    }
  }
  __syncthreads();

  // ---- phase 2: logits = S @ W ; wave owns k-cols [w*256, w*256+256) ----
  f32x4 acc0[16], acc1[16];
  #pragma unroll
  for (int ct=0;ct<16;ct++){ acc0[ct] = (f32x4){0.f,0.f,0.f,0.f}; acc1[ct] = (f32x4){0.f,0.f,0.f,0.f}; }
  {
    const u8* wbase = W8 + (size_t)(w*16)*1024 + lane*16;
    uint4 bv[8];
    #pragma unroll
    for (int ct=0; ct<8; ++ct) bv[ct] = *(const uint4*)(wbase + ct*1024);
    #pragma unroll 1
    for (int pt=0; pt<32; ++pt){
      const u8* sp0 = S + lc*SROW8 + q*8 + pt*64;
      long a0e = *(const long*)(sp0);
      long a0o = *(const long*)(sp0 + 32);
      long a1e = *(const long*)(sp0 + 16*SROW8);
      long a1o = *(const long*)(sp0 + 16*SROW8 + 32);
      const u8* wcur = wbase + (size_t)pt*131072;
      const u8* wnxt = wbase + (size_t)((pt+1)&31)*131072;
      uint4 bw[8];
      #pragma unroll
      for (int ct=0; ct<8; ++ct) bw[ct] = *(const uint4*)(wcur + (8+ct)*1024);
      #pragma unroll
      for (int ct=0; ct<8; ++ct){
        long be = lo64(bv[ct]), bo = hi64(bv[ct]);
        acc0[ct] = mfma_fp8(a0e, be, acc0[ct]);
        acc1[ct] = mfma_fp8(a1e, be, acc1[ct]);
        acc0[ct] = mfma_fp8(a0o, bo, acc0[ct]);
        acc1[ct] = mfma_fp8(a1o, bo, acc1[ct]);
      }
      #pragma unroll
      for (int ct=0; ct<8; ++ct) bv[ct] = *(const uint4*)(wnxt + ct*1024);
      #pragma unroll
      for (int ct=0; ct<8; ++ct){
        long be = lo64(bw[ct]), bo = hi64(bw[ct]);
        acc0[8+ct] = mfma_fp8(a0e, be, acc0[8+ct]);
        acc1[8+ct] = mfma_fp8(a1e, be, acc1[8+ct]);
        acc0[8+ct] = mfma_fp8(a0o, bo, acc0[8+ct]);
        acc1[8+ct] = mfma_fp8(a1o, bo, acc1[8+ct]);
      }
    }
  }

  // ---- phase 3: row softmax over k (true logits = 0.5*acc) ----
  float gmax0[4], gmax1[4], gsc0[4], gsc1[4];
  #pragma unroll
  for (int i=0;i<4;i++){
    float mx0 = acc0[0][i], mx1 = acc1[0][i];
    #pragma unroll
    for (int ct=1; ct<16; ++ct){ mx0 = fmaxf(mx0, acc0[ct][i]); mx1 = fmaxf(mx1, acc1[ct][i]); }
    mx0 = fmaxf(mx0, __shfl_xor(mx0, 1)); mx1 = fmaxf(mx1, __shfl_xor(mx1, 1));
    mx0 = fmaxf(mx0, __shfl_xor(mx0, 2)); mx1 = fmaxf(mx1, __shfl_xor(mx1, 2));
    mx0 = fmaxf(mx0, __shfl_xor(mx0, 4)); mx1 = fmaxf(mx1, __shfl_xor(mx1, 4));
    mx0 = fmaxf(mx0, __shfl_xor(mx0, 8)); mx1 = fmaxf(mx1, __shfl_xor(mx1, 8));
    if (lc == 0){ redm[q*4+i][w] = mx0; redm[16+q*4+i][w] = mx1; }
  }
  __syncthreads();
  #pragma unroll
  for (int i=0;i<4;i++){
    float m0 = redm[q*4+i][0], m1 = redm[16+q*4+i][0];
    #pragma unroll
    for (int j=1;j<8;j++){ m0 = fmaxf(m0, redm[q*4+i][j]); m1 = fmaxf(m1, redm[16+q*4+i][j]); }
    gmax0[i] = m0; gmax1[i] = m1;
  }
  #pragma unroll
  for (int i=0;i<4;i++){
    float s0 = 0.f, s1 = 0.f;
    #pragma unroll
    for (int ct=0; ct<16; ++ct){
      float e0 = __expf(0.5f*(acc0[ct][i] - gmax0[i]));
      float e1 = __expf(0.5f*(acc1[ct][i] - gmax1[i]));
      acc0[ct][i] = e0; acc1[ct][i] = e1;
      s0 += e0; s1 += e1;
    }
    s0 += __shfl_xor(s0, 1); s1 += __shfl_xor(s1, 1);
    s0 += __shfl_xor(s0, 2); s1 += __shfl_xor(s1, 2);
    s0 += __shfl_xor(s0, 4); s1 += __shfl_xor(s1, 4);
    s0 += __shfl_xor(s0, 8); s1 += __shfl_xor(s1, 8);
    if (lc == 0){ redsum[q*4+i][w] = s0; redsum[16+q*4+i][w] = s1; }
  }
  __syncthreads();
  #pragma unroll
  for (int i=0;i<4;i++){
    float s0 = 0.f, s1 = 0.f;
    #pragma unroll
    for (int j=0;j<8;j++){ s0 += redsum[q*4+i][j]; s1 += redsum[16+q*4+i][j]; }
    gsc0[i] = 256.f/s0; gsc1[i] = 256.f/s1;
  }
  #pragma unroll
  for (int ct=0; ct<16; ++ct){
    const int col = w*256 + ct*16 + lc;
    #pragma unroll
    for (int i=0;i<4;i++){
      S[(q*4+i)*SROW8 + col]      = f2fp8(acc0[ct][i]*gsc0[i]);
      S[(16+q*4+i)*SROW8 + col]   = f2fp8(acc1[ct][i]*gsc1[i]);
    }
  }
  __syncthreads();

  // ---- phase 4: out = (deg*256) @ h / 256, pipelined; fin fuses k_final ----
  {
    const int rt4 = w >> 2, dt = w & 3;
    f32x4 o = {0.f,0.f,0.f,0.f};
    const u8* abase = S + (size_t)(rt4*16 + lc)*SROW8 + q*8;
    const u8* bbase = htb + (size_t)dt*1024 + lane*16;
    uint4 bcur = *(const uint4*)(bbase);
    #pragma unroll 1
    for (int pt=0; pt<32; ++pt){
      uint4 bnxt = *(const uint4*)(bbase + (size_t)((pt+1)&31)*4096);
      long ae = *(const long*)(abase + pt*64);
      long ao = *(const long*)(abase + pt*64 + 32);
      o = mfma_fp8(ae, lo64(bcur), o);
      o = mfma_fp8(ao, hi64(bcur), o);
      bcur = bnxt;
    }
    float* op = outp + (size_t)b*2048*64;
    const float* hp = hf32 + (size_t)b*2048*64;
    const float* cp = oc_in + (size_t)b*2048*64;
    #pragma unroll
    for (int i=0;i<4;i++){
      size_t idx = (size_t)(n0 + rt4*16 + q*4 + i)*64 + dt*16 + lc;
      float v = o[i]*(1.f/256.f);
      if (fin) v = 0.8f*hp[idx] - 0.1f*cp[idx] + 0.1f*v;
      op[idx] = v;
    }
  }
}

// ---------------------------------------------------------------------------
extern "C" void kernel_launch(void* const* d_in, const int* in_sizes, int n_in,
                              void* d_out, int out_size, void* d_ws, size_t ws_size,
                              hipStream_t stream) {
  const float* x     = (const float*)d_in[0];
  const float* state = (const float*)d_in[1];
  const float* E     = (const float*)d_in[2];
  const float* Wc    = (const float*)d_in[3];
  const float* Wd    = (const float*)d_in[4];
  const float* gw    = (const float*)d_in[5];
  const float* gb    = (const float*)d_in[6];
  const float* uw    = (const float*)d_in[7];
  const float* ub    = (const float*)d_in[8];

  // workspace layout (bytes). Total 73,662,464 B = 70.2 MB (same as round 7).
  char* base = (char*)d_ws;
  u16*   P    = (u16*)(base + 0);           //  8,388,608  (dead after 2nd k_conv)
  u32*   mp2  = (u32*)(base + 0);           //    524,288  (aliases P; written after P dead)
  u32*   mn2  = (u32*)(base + 524288);      //    524,288  (aliases P)
  u8*    msk  = (u8*) (base + 8388608);     //  4,194,304
  u8*    Wc8  = (u8*) (base + 12582912);    //  4,194,304
  u8*    Wd8  = (u8*) (base + 16777216);    //  4,194,304
  u16*   hb16 = (u16*)(base + 20971520);    //  4,194,304
  u8*    ht8p = (u8*) (base + 25165824);    //  2,097,152
  u16*   hfm  = (u16*)(base + 27262976);    //  4,194,304
  float* c1x  = (float*)(base + 31457280);  //    262,144
  float* c1s  = (float*)(base + 31719424);  //  8,388,608
  float* zs   = (float*)(base + 40108032);  //  8,388,608
  float* rws  = (float*)(base + 48496640);  //  8,388,608
  float* c2s  = (float*)(base + 56885248);  //  8,388,608
  float* h    = (float*)(base + 65273856);  //  8,388,608
  float* oc   = c1s;                        // dead after k_gate
  float* od   = c2s;                        // dead after k_upd (unused placeholder)

  k_w8<<<dim3(32,32,2), 256, 0, stream>>>(Wc, Wd, Wc8, Wd8);
  k_P<<<2048, 256, 0, stream>>>(E, P, msk);
  k_c1x<<<dim3(32,16), 128, 0, stream>>>(P, x, c1x);
  k_conv<<<dim3(32,16), 256, 0, stream>>>(P, state, c1s);
  k_gate<<<2048, 256, 0, stream>>>(E, gw, gb, x, state, c1x, c1s, zs, rws);
  k_conv<<<dim3(32,16), 256, 0, stream>>>(P, zs, c2s);
  k_upd<<<2048, 256, 0, stream>>>(E, uw, ub, x, state, zs, c1x, c2s, rws, h);
  k_hcvt<<<dim3(32,16), 256, 0, stream>>>(h, hb16, ht8p, hfm);
  k_mbits<<<dim3(2048,8), 256, 0, stream>>>(msk, mp2, mn2);   // P dead by now

  const int deg_lds = 32*SROW8;   // 65,792 B dynamic
  hipFuncSetAttribute((const void*)k_deg, hipFuncAttributeMaxDynamicSharedMemorySize, deg_lds);
  // dispatch 1: connect mask — only Wc8 hot in every XCD L2
  k_deg<<<1024, 512, deg_lds, stream>>>(mp2, hb16, Wc8, ht8p, hfm, h, h, oc, 0);
  // dispatch 2: disconnect mask — only Wd8 hot; fused final epilogue -> d_out
  k_deg<<<1024, 512, deg_lds, stream>>>(mn2, hb16, Wd8, ht8p, hfm, h, oc, (float*)d_out, 1);
}